// Round 13
// baseline (179.431 us; speedup 1.0000x reference)
//
#include <hip/hip_runtime.h>
#include <hip/hip_bf16.h>

#define N_SUP 16384
#define M_Q   4096
#define TV    27
#define CIN   41
#define CH1   864
#define CH2   128
#define CAP   1024
#define NB    12          // bins per xy axis (width 50/12 = 4.17 >= 4)
#define NEAR2 14.0625f    // 3.75^2 near/far partition threshold on dq^2

// kC tiling: 16x64 tile, 256 threads (4 waves), 2x2/thread, grid 512 -> 8 waves/CU
#define C2BM 16
#define C2BN 64
#define C2BK 32

// grid offset value for axis-index 0/1/2 : linspace(-R+R/NV, R-R/NV, 3) = {-1.3333334, 0, +1.3333334}
__device__ __forceinline__ float gsel(int i){
  const float GOFF = (float)(-2.0 + 2.0 / 3.0);   // -1.3333334f (matches f32 linspace endpoint)
  return (i == 0) ? GOFF : ((i == 2) ? -GOFF : 0.0f);
}

__device__ __forceinline__ int binOf(float x){
  int b = (int)(x * (float)(NB / 50.0));
  return (b < 0) ? 0 : ((b > NB - 1) ? NB - 1 : b);
}

// branchless 3-deep insert of u64 key (keeps k0 <= k1 <= k2)
__device__ __forceinline__ void insK(unsigned long long key,
                                     unsigned long long& k0,
                                     unsigned long long& k1,
                                     unsigned long long& k2){
  bool b0 = key < k0, b1 = key < k1, b2 = key < k2;
  k2 = b1 ? k1 : (b2 ? key : k2);
  k1 = b0 ? k0 : (b1 ? key : k1);
  k0 = b0 ? key : k0;
}

// ---------------- Kernel Pre: w1/w2 transpose + support-point bin count (fused) ----------------
__global__ void kPre(const float* __restrict__ w1, float* __restrict__ w1T,
                     const float* __restrict__ w2, float* __restrict__ w2T,
                     const float* __restrict__ sup_xyz, int* __restrict__ counts)
{
  int idx = blockIdx.x * 256 + threadIdx.x;
  if (idx < N_SUP) {
    float x = sup_xyz[3*idx], y = sup_xyz[3*idx+1];
    atomicAdd(&counts[binOf(x) * NB + binOf(y)], 1);
  }
  if (idx < CIN * CH1) {
    int k = idx / CH1, t = idx % CH1;
    w1T[idx] = w1[(size_t)t * CIN + k];
  }
  int j = idx - CIN * CH1;
  if (j >= 0 && j < CH1 * CH2) {
    int k = j / CH2, c = j % CH2;
    w2T[j] = w2[(size_t)c * CH1 + k];
  }
}

__global__ void kScan(const int* __restrict__ counts, int* __restrict__ starts, int* __restrict__ cursor)
{
  __shared__ int sc[NB*NB];
  int t = threadIdx.x;
  if (t < NB*NB) sc[t] = counts[t];
  __syncthreads();
  if (t == 0) {
    int acc = 0;
    for (int b = 0; b < NB*NB; b++) { int c = sc[b]; sc[b] = acc; acc += c; }
  }
  __syncthreads();
  if (t < NB*NB) { starts[t] = sc[t]; cursor[t] = sc[t]; }
  if (t == NB*NB) starts[NB*NB] = N_SUP;
}

__global__ void kScatter(const float* __restrict__ sup_xyz, int* __restrict__ cursor,
                         float* __restrict__ xs, float* __restrict__ ys,
                         float* __restrict__ zs, int* __restrict__ sid)
{
  int i = blockIdx.x * 256 + threadIdx.x;
  if (i < N_SUP) {
    float x = sup_xyz[3*i], y = sup_xyz[3*i+1], z = sup_xyz[3*i+2];
    int b = binOf(x) * NB + binOf(y);
    int p = atomicAdd(&cursor[b], 1);
    xs[p] = x; ys[p] = y; zs[p] = z; sid[p] = i;
  }
}

// ---------------- Kernel A12: cube filter w/ near-far partition + per-voxel 3NN ----------------
__global__ __launch_bounds__(256) void kA12(const float* __restrict__ xs,
                                            const float* __restrict__ ys,
                                            const float* __restrict__ zs,
                                            const int*   __restrict__ sid,
                                            const int*   __restrict__ starts,
                                            const float* __restrict__ new_xyz,
                                            const float* __restrict__ sup_xyz,
                                            float* __restrict__ nnW,
                                            int*   __restrict__ nnGI,
                                            float* __restrict__ nnLX)
{
  __shared__ float4 cxyz[CAP];                 // near from front, far from back; .w = sid bits
  __shared__ unsigned long long sk[TV][8][3];
  __shared__ int s_nc, s_fc;

  const int m   = blockIdx.x;
  const int tid = threadIdx.x;
  if (tid == 0) { s_nc = 0; s_fc = 0; }
  __syncthreads();

  const float qx = new_xyz[m*3+0];
  const float qy = new_xyz[m*3+1];
  const float qz = new_xyz[m*3+2];

  // ---- phase 1: cube filter over <=3x3 bins (z-test vacuous) + near/far partition ----
  const int bx0 = binOf(qx - 4.0f), bx1 = binOf(qx + 4.0f);
  const int by0 = binOf(qy - 4.0f), by1 = binOf(qy + 4.0f);
  for (int bx = bx0; bx <= bx1; bx++) {
    const int beg = starts[bx * NB + by0];
    const int end = starts[bx * NB + by1 + 1];
    for (int i = beg + tid; i < end; i += 256) {
      float x = xs[i], y = ys[i];
      float dx = __fsub_rn(x, qx), dy = __fsub_rn(y, qy);
      if (fabsf(dx) <= 4.0f && fabsf(dy) <= 4.0f) {
        float z = zs[i];
        float dz = __fsub_rn(z, qz);
        float dq2 = __fadd_rn(__fadd_rn(__fmul_rn(dx,dx), __fmul_rn(dy,dy)), __fmul_rn(dz,dz));
        float4 val = make_float4(x, y, z, __uint_as_float((unsigned)sid[i]));
        if (dq2 <= NEAR2) {
          int p = atomicAdd(&s_nc, 1);
          if (p < CAP) cxyz[p] = val;
        } else {
          int p = atomicAdd(&s_fc, 1);
          int idx2 = CAP - 1 - p;
          if (idx2 >= 0) cxyz[idx2] = val;
        }
      }
    }
  }
  __syncthreads();
  const int ncnt = (s_nc < CAP) ? s_nc : CAP;
  const int fcnt = (s_fc < CAP) ? s_fc : CAP;
  const int cnt  = ncnt + fcnt;
  const int farBeg = CAP - fcnt;

  // ---- phase 2a: near-list strided scan, 8 threads per voxel, guarded insert ----
  const int v = tid >> 3, j = tid & 7;
  if (v < TV) {
    const float gx = qx + gsel(v / 9);
    const float gy = qy + gsel((v / 3) % 3);
    const float gz = qz + gsel(v % 3);
    unsigned long long k0 = ~0ull, k1 = ~0ull, k2 = ~0ull;
    float k2df = __uint_as_float(0xFFFFFFFFu);   // NaN sentinel -> insert path until 3 found
    for (int c = j; c < ncnt; c += 8) {
      float4 f4 = cxyz[c];
      float dx = __fsub_rn(gx, f4.x);
      float dy = __fsub_rn(gy, f4.y);
      float dz = __fsub_rn(gz, f4.z);
      // forbid FMA contraction: must match numpy f32 (mul, mul, add, mul, add)
      float dd = __fadd_rn(__fadd_rn(__fmul_rn(dx,dx), __fmul_rn(dy,dy)), __fmul_rn(dz,dz));
      if (!(dd > k2df)) {                        // fast reject; == still takes insert (tie by sid)
        unsigned long long key = ((unsigned long long)__float_as_uint(dd) << 32)
                               | (unsigned long long)__float_as_uint(f4.w); // low = sid
        insK(key, k0, k1, k2);
        k2df = __uint_as_float((unsigned)(k2 >> 32));
      }
    }
    sk[v][j][0] = k0; sk[v][j][1] = k1; sk[v][j][2] = k2;
  }
  __syncthreads();

  // ---- phase 2b: merge, completeness check, (rare) far-list fallback, emit ----
  if (tid < TV) {
    const int vv = tid;
    const float ox = gsel(vv / 9), oy = gsel((vv / 3) % 3), oz = gsel(vv % 3);
    const float gx = qx + ox, gy = qy + oy, gz = qz + oz;
    const float dgq = sqrtf(ox*ox + oy*oy + oz*oz) + 1e-3f;   // upper bound of |g-q|

    unsigned long long k0 = ~0ull, k1 = ~0ull, k2 = ~0ull;
    #pragma unroll
    for (int jj = 0; jj < 8; jj++) {
      insK(sk[vv][jj][0], k0, k1, k2);
      insK(sk[vv][jj][1], k0, k1, k2);
      insK(sk[vv][jj][2], k0, k1, k2);
    }
    float k2df = __uint_as_float((unsigned)(k2 >> 32));   // NaN if <3 found
    // far list can contain a top-3 member only if sqrt(k2)+dgq reaches past 3.7499
    // (far => true dq > 3.74999; dist to voxel >= dq - dgq). NaN -> check false -> fallback.
    if (!(sqrtf(k2df) * 1.00002f + dgq <= 3.7498f)) {
      for (int c = farBeg; c < CAP; c++) {
        float4 f4 = cxyz[c];
        float dx = __fsub_rn(gx, f4.x);
        float dy = __fsub_rn(gy, f4.y);
        float dz = __fsub_rn(gz, f4.z);
        float dd = __fadd_rn(__fadd_rn(__fmul_rn(dx,dx), __fmul_rn(dy,dy)), __fmul_rn(dz,dz));
        if (!(dd > k2df)) {
          unsigned long long key = ((unsigned long long)__float_as_uint(dd) << 32)
                                 | (unsigned long long)__float_as_uint(f4.w);
          insK(key, k0, k1, k2);
          k2df = __uint_as_float((unsigned)(k2 >> 32));
        }
      }
    }

    const int base = m * TV + vv;
    if (cnt > 0) {
      unsigned long long ks[3] = {k0, k1, k2};
      float d[3]; int gi[3]; bool ok[3];
      #pragma unroll
      for (int r = 0; r < 3; r++) {
        unsigned db = (unsigned)(ks[r] >> 32);
        ok[r] = (db != 0xFFFFFFFFu);
        d[r]  = ok[r] ? __uint_as_float(db) : 1e10f;
        gi[r] = ok[r] ? (int)(unsigned)(ks[r] & 0xFFFFFFFFull) : 0;
      }
      float r0 = 1.0f / (d[0] + 1e-8f);
      float r1 = 1.0f / (d[1] + 1e-8f);
      float r2 = 1.0f / (d[2] + 1e-8f);
      float den = fmaxf(r0 + r1 + r2, 1e-8f);
      nnW[base*3+0] = r0 / den; nnW[base*3+1] = r1 / den; nnW[base*3+2] = r2 / den;
      nnGI[base*3+0] = gi[0]; nnGI[base*3+1] = gi[1]; nnGI[base*3+2] = gi[2];
      #pragma unroll
      for (int r = 0; r < 3; r++) {
        if (ok[r]) {
          nnLX[base*9 + r*3 + 0] = gx - sup_xyz[gi[r]*3 + 0];
          nnLX[base*9 + r*3 + 1] = gy - sup_xyz[gi[r]*3 + 1];
          nnLX[base*9 + r*3 + 2] = gz - sup_xyz[gi[r]*3 + 2];
        } else {
          nnLX[base*9 + r*3 + 0] = 0.0f;
          nnLX[base*9 + r*3 + 1] = 0.0f;
          nnLX[base*9 + r*3 + 2] = 0.0f;
        }
      }
    } else {
      #pragma unroll
      for (int r = 0; r < 3; r++) {
        nnW[base*3+r] = 0.0f; nnGI[base*3+r] = 0;
        nnLX[base*9+r*3+0] = 0.0f; nnLX[base*9+r*3+1] = 0.0f; nnLX[base*9+r*3+2] = 0.0f;
      }
    }
  }
}

// ---------------- Kernel A3: interp features + grouped conv1, 8 queries per block ----------------
__global__ __launch_bounds__(256) void kA3(const float* __restrict__ sup_feat,
                                           const float* __restrict__ nnW,
                                           const int*   __restrict__ nnGI,
                                           const float* __restrict__ nnLX,
                                           const float* __restrict__ w1T,
                                           float* __restrict__ y1)
{
  __shared__ float s_feats[8][TV][CIN];
  __shared__ float s_w[8][TV][3];
  __shared__ int   s_gi[8][TV][3];

  const int m0  = blockIdx.x * 8;
  const int tid = threadIdx.x;

  for (int t = tid; t < 8*TV*3; t += 256) {
    int q = t / (TV*3), rem = t % (TV*3);
    s_w[q][rem/3][rem%3]  = nnW[m0*TV*3 + t];
    s_gi[q][rem/3][rem%3] = nnGI[m0*TV*3 + t];
  }
  for (int t = tid; t < 8*TV*9; t += 256) {
    int q = t / (TV*9), rem = t % (TV*9);
    s_feats[q][rem/9][32 + rem%9] = nnLX[m0*TV*9 + t];
  }
  __syncthreads();

  for (int t = tid; t < 8*TV*32; t += 256) {
    const int q = t / (TV*32), rem = t % (TV*32);
    const int v = rem >> 5, ch = rem & 31;
    s_feats[q][v][ch] = s_w[q][v][0] * sup_feat[s_gi[q][v][0]*32 + ch]
                      + s_w[q][v][1] * sup_feat[s_gi[q][v][1]*32 + ch]
                      + s_w[q][v][2] * sup_feat[s_gi[q][v][2]*32 + ch];
  }
  __syncthreads();

  for (int t = tid; t < CH1; t += 256) {
    const int v = t >> 5;
    float acc[8];
    #pragma unroll
    for (int q = 0; q < 8; q++) acc[q] = 0.0f;
    for (int k = 0; k < CIN; k++) {
      float w = w1T[k * CH1 + t];
      #pragma unroll
      for (int q = 0; q < 8; q++) acc[q] += s_feats[q][v][k] * w;
    }
    #pragma unroll
    for (int q = 0; q < 8; q++) y1[(size_t)(m0 + q) * CH1 + t] = acc[q];
  }
}

// ---------------- Kernel B: BN1 stats ----------------
__global__ void kB(const float* __restrict__ y1, float* __restrict__ stats1)
{
  const int c  = threadIdx.x;        // 864 threads
  const int m0 = blockIdx.x * 64;    // 64 blocks
  float s = 0.0f, ss = 0.0f;
  for (int r = 0; r < 64; r++) {
    float v = y1[(size_t)(m0 + r) * CH1 + c];
    s += v; ss += v * v;
  }
  atomicAdd(&stats1[c],       s);
  atomicAdd(&stats1[CH1 + c], ss);
}

// ---------------- Kernel S: BN1 scale/shift precompute ----------------
__global__ void kS(const float* __restrict__ stats1,
                   const float* __restrict__ g1, const float* __restrict__ b1,
                   float* __restrict__ scsg, float* __restrict__ shsg)
{
  int c = blockIdx.x * 256 + threadIdx.x;
  if (c < CH1) {
    float s  = stats1[c], ssq = stats1[CH1 + c];
    float mu  = s  * (1.0f / M_Q);
    float var = ssq * (1.0f / M_Q) - mu * mu;
    float r   = 1.0f / sqrtf(var + 1e-5f);
    float gg = g1[c];
    scsg[c] = r * gg;
    shsg[c] = b1[c] - mu * r * gg;
  }
}

// ---------------- Kernel C: BN1-fused GEMM, 16x64 tile, 4 waves/block, 2x2/thread, grid 512 ----------------
__global__ __launch_bounds__(256) void kC(const float* __restrict__ y1,
                                          const float* __restrict__ scsg,
                                          const float* __restrict__ shsg,
                                          const float* __restrict__ w2T,
                                          float* __restrict__ z,
                                          float* __restrict__ stats2)   // [8][256]
{
  __shared__ float As[C2BK][21];      // [k][row], stride 21: conflict-free stores/reads
  __shared__ float Bs[C2BK][C2BN];    // 8 KB
  __shared__ float st_s[2][C2BN];

  const int tid = threadIdx.x;
  const int m0  = (blockIdx.x >> 1) * C2BM;
  const int bn0 = (blockIdx.x & 1) * C2BN;

  if (tid < 2*C2BN) st_s[tid >> 6][tid & 63] = 0.0f;

  const int arow = tid >> 4;
  const int akp  = (tid & 15) * 2;
  const int bkk = tid >> 3;
  const int bc8 = (tid & 7) * 8;
  const int ty = tid >> 5;
  const int tx = tid & 31;

  float2 pa  = *(const float2*)&y1[(size_t)(m0 + arow) * CH1 + akp];
  float2 psc = *(const float2*)&scsg[akp];
  float2 psh = *(const float2*)&shsg[akp];
  float4 pb0 = *(const float4*)&w2T[(size_t)bkk * CH2 + bn0 + bc8];
  float4 pb1 = *(const float4*)&w2T[(size_t)bkk * CH2 + bn0 + bc8 + 4];

  float a00 = 0.f, a01 = 0.f, a10 = 0.f, a11 = 0.f;

  for (int k0 = 0; k0 < CH1; k0 += C2BK) {
    __syncthreads();
    As[akp  ][arow] = fmaxf(pa.x * psc.x + psh.x, 0.0f);
    As[akp+1][arow] = fmaxf(pa.y * psc.y + psh.y, 0.0f);
    *(float4*)&Bs[bkk][bc8]     = pb0;
    *(float4*)&Bs[bkk][bc8 + 4] = pb1;
    __syncthreads();
    const int kn = k0 + C2BK;
    if (kn < CH1) {
      pa  = *(const float2*)&y1[(size_t)(m0 + arow) * CH1 + kn + akp];
      psc = *(const float2*)&scsg[kn + akp];
      psh = *(const float2*)&shsg[kn + akp];
      pb0 = *(const float4*)&w2T[(size_t)(kn + bkk) * CH2 + bn0 + bc8];
      pb1 = *(const float4*)&w2T[(size_t)(kn + bkk) * CH2 + bn0 + bc8 + 4];
    }
    #pragma unroll
    for (int kk = 0; kk < C2BK; kk++) {
      float2 av = *(const float2*)&As[kk][ty*2];
      float2 bv = *(const float2*)&Bs[kk][tx*2];
      a00 += av.x*bv.x; a01 += av.x*bv.y;
      a10 += av.y*bv.x; a11 += av.y*bv.y;
    }
  }

  *(float2*)&z[(size_t)(m0 + ty*2    ) * CH2 + bn0 + tx*2] = make_float2(a00, a01);
  *(float2*)&z[(size_t)(m0 + ty*2 + 1) * CH2 + bn0 + tx*2] = make_float2(a10, a11);

  atomicAdd(&st_s[0][tx*2    ], a00 + a10);
  atomicAdd(&st_s[0][tx*2 + 1], a01 + a11);
  atomicAdd(&st_s[1][tx*2    ], a00*a00 + a10*a10);
  atomicAdd(&st_s[1][tx*2 + 1], a01*a01 + a11*a11);
  __syncthreads();
  if (tid < 2*C2BN) {
    int which = tid >> 6, c = tid & 63;
    int copy = (blockIdx.x >> 1) & 7;
    atomicAdd(&stats2[copy*256 + which*128 + bn0 + c], st_s[which][c]);
  }
}

// ---------------- Kernel D: BN2 apply + ReLU -> f32 out ----------------
__global__ void kD(const float* __restrict__ z,
                   const float* __restrict__ stats2,   // [8][256]
                   const float* __restrict__ g2,
                   const float* __restrict__ b2,
                   float* __restrict__ out)
{
  int t = blockIdx.x * 256 + threadIdx.x;
  if (t >= M_Q * CH2) return;
  int c = t & 127;
  float s = 0.0f, ss = 0.0f;
  #pragma unroll
  for (int k = 0; k < 8; k++) {
    s  += stats2[k * 256 + c];
    ss += stats2[k * 256 + 128 + c];
  }
  float mu  = s  * (1.0f / M_Q);
  float var = ss * (1.0f / M_Q) - mu * mu;
  float r   = 1.0f / sqrtf(var + 1e-5f);
  float val = fmaxf((z[t] - mu) * r * g2[c] + b2[c], 0.0f);
  out[t] = val;
}

extern "C" void kernel_launch(void* const* d_in, const int* in_sizes, int n_in,
                              void* d_out, int out_size, void* d_ws, size_t ws_size,
                              hipStream_t stream)
{
  const float* sup_xyz  = (const float*)d_in[0];
  const float* sup_feat = (const float*)d_in[1];
  const float* new_xyz  = (const float*)d_in[2];
  const float* w1       = (const float*)d_in[3];
  const float* g1       = (const float*)d_in[4];
  const float* b1       = (const float*)d_in[5];
  const float* w2       = (const float*)d_in[6];
  const float* g2       = (const float*)d_in[7];
  const float* b2       = (const float*)d_in[8];
  float* out = (float*)d_out;

  char* ws = (char*)d_ws;
  float* y1     = (float*)(ws);                       // 14,155,776 B
  float* z      = (float*)(ws + 14155776);            //  2,097,152 B (aliased by w1T early)
  float* w2T    = (float*)(ws + 16252928);            //    442,368 B
  float* stats  = (float*)(ws + 16695296);            //     15,104 B (1728 + 2048 f32)
  int*   counts = (int*)  (ws + 16710400);            //        576 B
  int*   cursor = (int*)  (ws + 16710976);            //        576 B
  int*   starts = (int*)  (ws + 16711552);            //        580 B
  float* xs     = (float*)(ws + 16712132);            //     65,536 B
  float* ys     = (float*)(ws + 16777668);
  float* zs     = (float*)(ws + 16843204);
  int*   sid    = (int*)  (ws + 16908740);
  float* nnW    = (float*)(ws + 16974276);            //  1,327,104 B
  int*   nnGI   = (int*)  (ws + 18301380);            //  1,327,104 B
  float* nnLX   = (float*)(ws + 19628484);            //  3,981,312 B  (end 23,609,796)
  float* stats1 = stats;
  float* stats2 = stats + 2 * CH1;                    // 8 copies x 256
  // w1T (141,696 B) aliases z: kA3 (last reader) runs before kC (writer of z).
  float* w1T    = z;
  // scsg/shsg (3456 B each) alias xs/ys: dead after kA12; kS rewrites before kC reads.
  float* scsg   = xs;
  float* shsg   = ys;

  // zero stats + counts + cursor in one contiguous memset
  hipMemsetAsync(stats, 0, 15104 + 576 + 576, stream);

  const int PRE_TOT = CIN*CH1 + CH1*CH2;              // covers N_SUP too
  hipLaunchKernelGGL(kPre,    dim3((PRE_TOT + 255) / 256), dim3(256), 0, stream, w1, w1T, w2, w2T, sup_xyz, counts);
  hipLaunchKernelGGL(kScan,   dim3(1),                    dim3(256), 0, stream, counts, starts, cursor);
  hipLaunchKernelGGL(kScatter,dim3((N_SUP + 255) / 256),  dim3(256), 0, stream, sup_xyz, cursor, xs, ys, zs, sid);
  hipLaunchKernelGGL(kA12,    dim3(M_Q),                  dim3(256), 0, stream, xs, ys, zs, sid, starts, new_xyz, sup_xyz, nnW, nnGI, nnLX);
  hipLaunchKernelGGL(kA3,     dim3(M_Q / 8),              dim3(256), 0, stream, sup_feat, nnW, nnGI, nnLX, w1T, y1);
  hipLaunchKernelGGL(kB,      dim3(M_Q / 64),             dim3(CH1), 0, stream, y1, stats1);
  hipLaunchKernelGGL(kS,      dim3((CH1 + 255) / 256),    dim3(256), 0, stream, stats1, g1, b1, scsg, shsg);
  hipLaunchKernelGGL(kC,      dim3((M_Q / C2BM) * 2),     dim3(256), 0, stream, y1, scsg, shsg, w2T, z, stats2);
  hipLaunchKernelGGL(kD,      dim3((M_Q*CH2 + 255) / 256),dim3(256), 0, stream, z, stats2, g2, b2, out);
}

// Round 14
// 156.622 us; speedup vs baseline: 1.1456x; 1.1456x over previous
//
#include <hip/hip_runtime.h>
#include <hip/hip_bf16.h>

#define N_SUP 16384
#define M_Q   4096
#define TV    27
#define CIN   41
#define CH1   864
#define CH2   128
#define CAP   1024
#define NB    12          // bins per xy axis (width 50/12 = 4.17 >= 4)

// kC tiling: 16x64 tile, 256 threads (4 waves), 2x2/thread, grid 512 -> 8 waves/CU
#define C2BM 16
#define C2BN 64
#define C2BK 32

// grid offset value for axis-index 0/1/2 : linspace(-R+R/NV, R-R/NV, 3) = {-1.3333334, 0, +1.3333334}
__device__ __forceinline__ float gsel(int i){
  const float GOFF = (float)(-2.0 + 2.0 / 3.0);   // -1.3333334f (matches f32 linspace endpoint)
  return (i == 0) ? GOFF : ((i == 2) ? -GOFF : 0.0f);
}

__device__ __forceinline__ int binOf(float x){
  int b = (int)(x * (float)(NB / 50.0));
  return (b < 0) ? 0 : ((b > NB - 1) ? NB - 1 : b);
}

// branchless 3-deep insert of u64 key (keeps k0 <= k1 <= k2)
__device__ __forceinline__ void insK(unsigned long long key,
                                     unsigned long long& k0,
                                     unsigned long long& k1,
                                     unsigned long long& k2){
  bool b0 = key < k0, b1 = key < k1, b2 = key < k2;
  k2 = b1 ? k1 : (b2 ? key : k2);
  k1 = b0 ? k0 : (b1 ? key : k1);
  k0 = b0 ? key : k0;
}

// ---------------- Kernel Pre: w1/w2 transpose + support-point bin count (fused) ----------------
__global__ void kPre(const float* __restrict__ w1, float* __restrict__ w1T,
                     const float* __restrict__ w2, float* __restrict__ w2T,
                     const float* __restrict__ sup_xyz, int* __restrict__ counts)
{
  int idx = blockIdx.x * 256 + threadIdx.x;
  if (idx < N_SUP) {
    float x = sup_xyz[3*idx], y = sup_xyz[3*idx+1];
    atomicAdd(&counts[binOf(x) * NB + binOf(y)], 1);
  }
  if (idx < CIN * CH1) {
    int k = idx / CH1, t = idx % CH1;
    w1T[idx] = w1[(size_t)t * CIN + k];
  }
  int j = idx - CIN * CH1;
  if (j >= 0 && j < CH1 * CH2) {
    int k = j / CH2, c = j % CH2;
    w2T[j] = w2[(size_t)c * CH1 + k];
  }
}

__global__ void kScan(const int* __restrict__ counts, int* __restrict__ starts, int* __restrict__ cursor)
{
  __shared__ int sc[NB*NB];
  int t = threadIdx.x;
  if (t < NB*NB) sc[t] = counts[t];
  __syncthreads();
  if (t == 0) {
    int acc = 0;
    for (int b = 0; b < NB*NB; b++) { int c = sc[b]; sc[b] = acc; acc += c; }
  }
  __syncthreads();
  if (t < NB*NB) { starts[t] = sc[t]; cursor[t] = sc[t]; }
  if (t == NB*NB) starts[NB*NB] = N_SUP;
}

__global__ void kScatter(const float* __restrict__ sup_xyz, int* __restrict__ cursor,
                         float* __restrict__ xs, float* __restrict__ ys,
                         float* __restrict__ zs, int* __restrict__ sid)
{
  int i = blockIdx.x * 256 + threadIdx.x;
  if (i < N_SUP) {
    float x = sup_xyz[3*i], y = sup_xyz[3*i+1], z = sup_xyz[3*i+2];
    int b = binOf(x) * NB + binOf(y);
    int p = atomicAdd(&cursor[b], 1);
    xs[p] = x; ys[p] = y; zs[p] = z; sid[p] = i;
  }
}

// ---------------- Kernel A12: bin-pruned cube filter + per-voxel 3NN (guarded insert) ----------------
// (byte-exact round-11 structure: flat scan, no sort/partition — empirically optimal)
__global__ __launch_bounds__(256) void kA12(const float* __restrict__ xs,
                                            const float* __restrict__ ys,
                                            const float* __restrict__ zs,
                                            const int*   __restrict__ sid,
                                            const int*   __restrict__ starts,
                                            const float* __restrict__ new_xyz,
                                            const float* __restrict__ sup_xyz,
                                            float* __restrict__ nnW,
                                            int*   __restrict__ nnGI,
                                            float* __restrict__ nnLX)
{
  __shared__ float4 cxyz[CAP];                 // filtered candidates (.w = sid bits)
  __shared__ unsigned long long sk[TV][8][3];
  __shared__ int s_cnt;

  const int m   = blockIdx.x;
  const int tid = threadIdx.x;
  if (tid == 0) s_cnt = 0;
  __syncthreads();

  const float qx = new_xyz[m*3+0];
  const float qy = new_xyz[m*3+1];
  const float qz = new_xyz[m*3+2];

  // ---- phase 1: cube filter over <=3x3 bins (z-test vacuous: |dz|<4 always) ----
  const int bx0 = binOf(qx - 4.0f), bx1 = binOf(qx + 4.0f);
  const int by0 = binOf(qy - 4.0f), by1 = binOf(qy + 4.0f);
  for (int bx = bx0; bx <= bx1; bx++) {
    const int beg = starts[bx * NB + by0];
    const int end = starts[bx * NB + by1 + 1];
    for (int i = beg + tid; i < end; i += 256) {
      float x = xs[i], y = ys[i];
      if (fabsf(__fsub_rn(x, qx)) <= 4.0f && fabsf(__fsub_rn(y, qy)) <= 4.0f) {
        int p = atomicAdd(&s_cnt, 1);
        if (p < CAP) cxyz[p] = make_float4(x, y, zs[i], __uint_as_float((unsigned)sid[i]));
      }
    }
  }
  __syncthreads();
  const int cnt = (s_cnt < CAP) ? s_cnt : CAP;

  // ---- phase 2a: strided scan, 8 threads per voxel, guarded insert ----
  const int v = tid >> 3, j = tid & 7;
  if (v < TV) {
    const float gx = qx + gsel(v / 9);
    const float gy = qy + gsel((v / 3) % 3);
    const float gz = qz + gsel(v % 3);
    unsigned long long k0 = ~0ull, k1 = ~0ull, k2 = ~0ull;
    float k2df = __uint_as_float(0xFFFFFFFFu);   // NaN sentinel -> insert path until 3 found
    for (int c = j; c < cnt; c += 8) {
      float4 f4 = cxyz[c];
      float dx = __fsub_rn(gx, f4.x);
      float dy = __fsub_rn(gy, f4.y);
      float dz = __fsub_rn(gz, f4.z);
      // forbid FMA contraction: must match numpy f32 (mul, mul, add, mul, add)
      float dd = __fadd_rn(__fadd_rn(__fmul_rn(dx,dx), __fmul_rn(dy,dy)), __fmul_rn(dz,dz));
      if (!(dd > k2df)) {                        // fast reject; == still takes insert (tie by sid)
        unsigned long long key = ((unsigned long long)__float_as_uint(dd) << 32)
                               | (unsigned long long)__float_as_uint(f4.w); // low = sid
        insK(key, k0, k1, k2);
        k2df = __uint_as_float((unsigned)(k2 >> 32));
      }
    }
    sk[v][j][0] = k0; sk[v][j][1] = k1; sk[v][j][2] = k2;
  }
  __syncthreads();

  // ---- phase 2b: merge 8x3 keys per voxel + emit (threads 0..26) ----
  if (tid < TV) {
    const int vv = tid;
    const float gx = qx + gsel(vv / 9);
    const float gy = qy + gsel((vv / 3) % 3);
    const float gz = qz + gsel(vv % 3);
    unsigned long long k0 = ~0ull, k1 = ~0ull, k2 = ~0ull;
    #pragma unroll
    for (int jj = 0; jj < 8; jj++) {
      insK(sk[vv][jj][0], k0, k1, k2);
      insK(sk[vv][jj][1], k0, k1, k2);
      insK(sk[vv][jj][2], k0, k1, k2);
    }
    const int base = m * TV + vv;
    if (cnt > 0) {
      unsigned long long ks[3] = {k0, k1, k2};
      float d[3]; int gi[3]; bool ok[3];
      #pragma unroll
      for (int r = 0; r < 3; r++) {
        unsigned db = (unsigned)(ks[r] >> 32);
        ok[r] = (db != 0xFFFFFFFFu);
        d[r]  = ok[r] ? __uint_as_float(db) : 1e10f;
        gi[r] = ok[r] ? (int)(unsigned)(ks[r] & 0xFFFFFFFFull) : 0;
      }
      float r0 = 1.0f / (d[0] + 1e-8f);
      float r1 = 1.0f / (d[1] + 1e-8f);
      float r2 = 1.0f / (d[2] + 1e-8f);
      float den = fmaxf(r0 + r1 + r2, 1e-8f);
      nnW[base*3+0] = r0 / den; nnW[base*3+1] = r1 / den; nnW[base*3+2] = r2 / den;
      nnGI[base*3+0] = gi[0]; nnGI[base*3+1] = gi[1]; nnGI[base*3+2] = gi[2];
      #pragma unroll
      for (int r = 0; r < 3; r++) {
        if (ok[r]) {
          nnLX[base*9 + r*3 + 0] = gx - sup_xyz[gi[r]*3 + 0];
          nnLX[base*9 + r*3 + 1] = gy - sup_xyz[gi[r]*3 + 1];
          nnLX[base*9 + r*3 + 2] = gz - sup_xyz[gi[r]*3 + 2];
        } else {
          nnLX[base*9 + r*3 + 0] = 0.0f;
          nnLX[base*9 + r*3 + 1] = 0.0f;
          nnLX[base*9 + r*3 + 2] = 0.0f;
        }
      }
    } else {
      #pragma unroll
      for (int r = 0; r < 3; r++) {
        nnW[base*3+r] = 0.0f; nnGI[base*3+r] = 0;
        nnLX[base*9+r*3+0] = 0.0f; nnLX[base*9+r*3+1] = 0.0f; nnLX[base*9+r*3+2] = 0.0f;
      }
    }
  }
}

// ---------------- Kernel A3: interp + grouped conv1 (8 queries/block) + fused BN1 stats ----------------
__global__ __launch_bounds__(256) void kA3(const float* __restrict__ sup_feat,
                                           const float* __restrict__ nnW,
                                           const int*   __restrict__ nnGI,
                                           const float* __restrict__ nnLX,
                                           const float* __restrict__ w1T,
                                           float* __restrict__ y1,
                                           float* __restrict__ stats1)   // [8][2*CH1]
{
  __shared__ float s_feats[8][TV][CIN];
  __shared__ float s_w[8][TV][3];
  __shared__ int   s_gi[8][TV][3];

  const int m0  = blockIdx.x * 8;
  const int tid = threadIdx.x;

  for (int t = tid; t < 8*TV*3; t += 256) {
    int q = t / (TV*3), rem = t % (TV*3);
    s_w[q][rem/3][rem%3]  = nnW[m0*TV*3 + t];
    s_gi[q][rem/3][rem%3] = nnGI[m0*TV*3 + t];
  }
  for (int t = tid; t < 8*TV*9; t += 256) {
    int q = t / (TV*9), rem = t % (TV*9);
    s_feats[q][rem/9][32 + rem%9] = nnLX[m0*TV*9 + t];
  }
  __syncthreads();

  for (int t = tid; t < 8*TV*32; t += 256) {
    const int q = t / (TV*32), rem = t % (TV*32);
    const int v = rem >> 5, ch = rem & 31;
    s_feats[q][v][ch] = s_w[q][v][0] * sup_feat[s_gi[q][v][0]*32 + ch]
                      + s_w[q][v][1] * sup_feat[s_gi[q][v][1]*32 + ch]
                      + s_w[q][v][2] * sup_feat[s_gi[q][v][2]*32 + ch];
  }
  __syncthreads();

  const int copy = (blockIdx.x & 7) * 2 * CH1;   // spread stat atomics over 8 copies
  for (int t = tid; t < CH1; t += 256) {
    const int v = t >> 5;
    float acc[8];
    #pragma unroll
    for (int q = 0; q < 8; q++) acc[q] = 0.0f;
    for (int k = 0; k < CIN; k++) {
      float w = w1T[k * CH1 + t];
      #pragma unroll
      for (int q = 0; q < 8; q++) acc[q] += s_feats[q][v][k] * w;
    }
    float s = 0.0f, ss = 0.0f;
    #pragma unroll
    for (int q = 0; q < 8; q++) {
      y1[(size_t)(m0 + q) * CH1 + t] = acc[q];
      s += acc[q]; ss += acc[q] * acc[q];
    }
    atomicAdd(&stats1[copy + t],       s);
    atomicAdd(&stats1[copy + CH1 + t], ss);
  }
}

// ---------------- Kernel S: BN1 scale/shift precompute (sums 8 stat copies) ----------------
__global__ void kS(const float* __restrict__ stats1,   // [8][2*CH1]
                   const float* __restrict__ g1, const float* __restrict__ b1,
                   float* __restrict__ scsg, float* __restrict__ shsg)
{
  int c = blockIdx.x * 256 + threadIdx.x;
  if (c < CH1) {
    float s = 0.0f, ssq = 0.0f;
    #pragma unroll
    for (int k = 0; k < 8; k++) {
      s   += stats1[k * 2 * CH1 + c];
      ssq += stats1[k * 2 * CH1 + CH1 + c];
    }
    float mu  = s  * (1.0f / M_Q);
    float var = ssq * (1.0f / M_Q) - mu * mu;
    float r   = 1.0f / sqrtf(var + 1e-5f);
    float gg = g1[c];
    scsg[c] = r * gg;
    shsg[c] = b1[c] - mu * r * gg;
  }
}

// ---------------- Kernel C: BN1-fused GEMM, 16x64 tile, 4 waves/block, 2x2/thread, grid 512 ----------------
__global__ __launch_bounds__(256) void kC(const float* __restrict__ y1,
                                          const float* __restrict__ scsg,
                                          const float* __restrict__ shsg,
                                          const float* __restrict__ w2T,
                                          float* __restrict__ z,
                                          float* __restrict__ stats2)   // [8][256]
{
  __shared__ float As[C2BK][21];      // [k][row], stride 21: conflict-free stores/reads
  __shared__ float Bs[C2BK][C2BN];    // 8 KB
  __shared__ float st_s[2][C2BN];

  const int tid = threadIdx.x;
  const int m0  = (blockIdx.x >> 1) * C2BM;
  const int bn0 = (blockIdx.x & 1) * C2BN;

  if (tid < 2*C2BN) st_s[tid >> 6][tid & 63] = 0.0f;

  const int arow = tid >> 4;
  const int akp  = (tid & 15) * 2;
  const int bkk = tid >> 3;
  const int bc8 = (tid & 7) * 8;
  const int ty = tid >> 5;
  const int tx = tid & 31;

  float2 pa  = *(const float2*)&y1[(size_t)(m0 + arow) * CH1 + akp];
  float2 psc = *(const float2*)&scsg[akp];
  float2 psh = *(const float2*)&shsg[akp];
  float4 pb0 = *(const float4*)&w2T[(size_t)bkk * CH2 + bn0 + bc8];
  float4 pb1 = *(const float4*)&w2T[(size_t)bkk * CH2 + bn0 + bc8 + 4];

  float a00 = 0.f, a01 = 0.f, a10 = 0.f, a11 = 0.f;

  for (int k0 = 0; k0 < CH1; k0 += C2BK) {
    __syncthreads();
    As[akp  ][arow] = fmaxf(pa.x * psc.x + psh.x, 0.0f);
    As[akp+1][arow] = fmaxf(pa.y * psc.y + psh.y, 0.0f);
    *(float4*)&Bs[bkk][bc8]     = pb0;
    *(float4*)&Bs[bkk][bc8 + 4] = pb1;
    __syncthreads();
    const int kn = k0 + C2BK;
    if (kn < CH1) {
      pa  = *(const float2*)&y1[(size_t)(m0 + arow) * CH1 + kn + akp];
      psc = *(const float2*)&scsg[kn + akp];
      psh = *(const float2*)&shsg[kn + akp];
      pb0 = *(const float4*)&w2T[(size_t)(kn + bkk) * CH2 + bn0 + bc8];
      pb1 = *(const float4*)&w2T[(size_t)(kn + bkk) * CH2 + bn0 + bc8 + 4];
    }
    #pragma unroll
    for (int kk = 0; kk < C2BK; kk++) {
      float2 av = *(const float2*)&As[kk][ty*2];
      float2 bv = *(const float2*)&Bs[kk][tx*2];
      a00 += av.x*bv.x; a01 += av.x*bv.y;
      a10 += av.y*bv.x; a11 += av.y*bv.y;
    }
  }

  *(float2*)&z[(size_t)(m0 + ty*2    ) * CH2 + bn0 + tx*2] = make_float2(a00, a01);
  *(float2*)&z[(size_t)(m0 + ty*2 + 1) * CH2 + bn0 + tx*2] = make_float2(a10, a11);

  atomicAdd(&st_s[0][tx*2    ], a00 + a10);
  atomicAdd(&st_s[0][tx*2 + 1], a01 + a11);
  atomicAdd(&st_s[1][tx*2    ], a00*a00 + a10*a10);
  atomicAdd(&st_s[1][tx*2 + 1], a01*a01 + a11*a11);
  __syncthreads();
  if (tid < 2*C2BN) {
    int which = tid >> 6, c = tid & 63;
    int copy = (blockIdx.x >> 1) & 7;
    atomicAdd(&stats2[copy*256 + which*128 + bn0 + c], st_s[which][c]);
  }
}

// ---------------- Kernel D: BN2 apply + ReLU -> f32 out (float4) ----------------
__global__ void kD(const float* __restrict__ z,
                   const float* __restrict__ stats2,   // [8][256]
                   const float* __restrict__ g2,
                   const float* __restrict__ b2,
                   float* __restrict__ out)
{
  int t4 = blockIdx.x * 256 + threadIdx.x;
  if (t4 >= M_Q * CH2 / 4) return;
  int c = (t4 & 31) * 4;
  float4 zv = *(const float4*)&z[(size_t)t4 * 4];
  float4 sv = make_float4(0,0,0,0), qv = make_float4(0,0,0,0);
  #pragma unroll
  for (int k = 0; k < 8; k++) {
    float4 a = *(const float4*)&stats2[k * 256 + c];
    float4 b = *(const float4*)&stats2[k * 256 + 128 + c];
    sv.x += a.x; sv.y += a.y; sv.z += a.z; sv.w += a.w;
    qv.x += b.x; qv.y += b.y; qv.z += b.z; qv.w += b.w;
  }
  float4 gv = *(const float4*)&g2[c];
  float4 bv = *(const float4*)&b2[c];
  float4 o;
  {
    float mu = sv.x * (1.0f/M_Q), var = qv.x * (1.0f/M_Q) - mu*mu;
    o.x = fmaxf((zv.x - mu) * (1.0f/sqrtf(var + 1e-5f)) * gv.x + bv.x, 0.0f);
  }
  {
    float mu = sv.y * (1.0f/M_Q), var = qv.y * (1.0f/M_Q) - mu*mu;
    o.y = fmaxf((zv.y - mu) * (1.0f/sqrtf(var + 1e-5f)) * gv.y + bv.y, 0.0f);
  }
  {
    float mu = sv.z * (1.0f/M_Q), var = qv.z * (1.0f/M_Q) - mu*mu;
    o.z = fmaxf((zv.z - mu) * (1.0f/sqrtf(var + 1e-5f)) * gv.z + bv.z, 0.0f);
  }
  {
    float mu = sv.w * (1.0f/M_Q), var = qv.w * (1.0f/M_Q) - mu*mu;
    o.w = fmaxf((zv.w - mu) * (1.0f/sqrtf(var + 1e-5f)) * gv.w + bv.w, 0.0f);
  }
  *(float4*)&out[(size_t)t4 * 4] = o;
}

extern "C" void kernel_launch(void* const* d_in, const int* in_sizes, int n_in,
                              void* d_out, int out_size, void* d_ws, size_t ws_size,
                              hipStream_t stream)
{
  const float* sup_xyz  = (const float*)d_in[0];
  const float* sup_feat = (const float*)d_in[1];
  const float* new_xyz  = (const float*)d_in[2];
  const float* w1       = (const float*)d_in[3];
  const float* g1       = (const float*)d_in[4];
  const float* b1       = (const float*)d_in[5];
  const float* w2       = (const float*)d_in[6];
  const float* g2       = (const float*)d_in[7];
  const float* b2       = (const float*)d_in[8];
  float* out = (float*)d_out;

  char* ws = (char*)d_ws;
  float* y1     = (float*)(ws);                       // 14,155,776 B
  float* z      = (float*)(ws + 14155776);            //  2,097,152 B (aliased by w1T early)
  float* w2T    = (float*)(ws + 16252928);            //    442,368 B
  float* stats1 = (float*)(ws + 16695296);            // 8 x 1728 f32 = 55,296 B
  float* stats2 = (float*)(ws + 16750592);            // 8 x  256 f32 =  8,192 B
  int*   counts = (int*)  (ws + 16758784);            //        576 B
  int*   cursor = (int*)  (ws + 16759360);            //        576 B
  int*   starts = (int*)  (ws + 16759936);            //        580 B
  float* xs     = (float*)(ws + 16760516);            //     65,536 B
  float* ys     = (float*)(ws + 16826052);
  float* zs     = (float*)(ws + 16891588);
  int*   sid    = (int*)  (ws + 16957124);
  float* nnW    = (float*)(ws + 17022660);            //  1,327,104 B
  int*   nnGI   = (int*)  (ws + 18349764);            //  1,327,104 B
  float* nnLX   = (float*)(ws + 19676868);            //  3,981,312 B  (end 23,658,180)
  // w1T (141,696 B) aliases z: kA3 (last reader) runs before kC (writer of z).
  float* w1T    = z;
  // scsg/shsg (3456 B each) alias xs/ys: dead after kA12; kS rewrites before kC reads.
  float* scsg   = xs;
  float* shsg   = ys;

  // zero stats1 + stats2 + counts + cursor in one contiguous memset
  hipMemsetAsync(stats1, 0, 55296 + 8192 + 576 + 576, stream);

  const int PRE_TOT = CIN*CH1 + CH1*CH2;              // covers N_SUP too
  hipLaunchKernelGGL(kPre,    dim3((PRE_TOT + 255) / 256), dim3(256), 0, stream, w1, w1T, w2, w2T, sup_xyz, counts);
  hipLaunchKernelGGL(kScan,   dim3(1),                    dim3(256), 0, stream, counts, starts, cursor);
  hipLaunchKernelGGL(kScatter,dim3((N_SUP + 255) / 256),  dim3(256), 0, stream, sup_xyz, cursor, xs, ys, zs, sid);
  hipLaunchKernelGGL(kA12,    dim3(M_Q),                  dim3(256), 0, stream, xs, ys, zs, sid, starts, new_xyz, sup_xyz, nnW, nnGI, nnLX);
  hipLaunchKernelGGL(kA3,     dim3(M_Q / 8),              dim3(256), 0, stream, sup_feat, nnW, nnGI, nnLX, w1T, y1, stats1);
  hipLaunchKernelGGL(kS,      dim3((CH1 + 255) / 256),    dim3(256), 0, stream, stats1, g1, b1, scsg, shsg);
  hipLaunchKernelGGL(kC,      dim3((M_Q / C2BM) * 2),     dim3(256), 0, stream, y1, scsg, shsg, w2T, z, stats2);
  hipLaunchKernelGGL(kD,      dim3(M_Q * CH2 / 4 / 256),  dim3(256), 0, stream, z, stats2, g2, b2, out);
}

// Round 15
// 150.463 us; speedup vs baseline: 1.1925x; 1.0409x over previous
//
#include <hip/hip_runtime.h>
#include <hip/hip_bf16.h>

#define N_SUP 16384
#define M_Q   4096
#define TV    27
#define CIN   41
#define CH1   864
#define CH2   128
#define CAP   1024
#define NB    12          // bins per xy axis (width 50/12 = 4.17 >= 4)

// kC split-K tiling: 32x128 tile, 4x4/thread, BK=24, 4 K-chunks of 216 -> grid 512, 2 waves/SIMD
#define KC_BK  24
#define KC_KS  216
#define KC_NCH 4

// grid offset value for axis-index 0/1/2 : linspace(-R+R/NV, R-R/NV, 3) = {-1.3333334, 0, +1.3333334}
__device__ __forceinline__ float gsel(int i){
  const float GOFF = (float)(-2.0 + 2.0 / 3.0);   // -1.3333334f (matches f32 linspace endpoint)
  return (i == 0) ? GOFF : ((i == 2) ? -GOFF : 0.0f);
}

__device__ __forceinline__ int binOf(float x){
  int b = (int)(x * (float)(NB / 50.0));
  return (b < 0) ? 0 : ((b > NB - 1) ? NB - 1 : b);
}

// branchless 3-deep insert of u64 key (keeps k0 <= k1 <= k2)
__device__ __forceinline__ void insK(unsigned long long key,
                                     unsigned long long& k0,
                                     unsigned long long& k1,
                                     unsigned long long& k2){
  bool b0 = key < k0, b1 = key < k1, b2 = key < k2;
  k2 = b1 ? k1 : (b2 ? key : k2);
  k1 = b0 ? k0 : (b1 ? key : k1);
  k0 = b0 ? key : k0;
}

// ---------------- Kernel Pre: w1/w2 transpose + support-point bin count (fused) ----------------
__global__ void kPre(const float* __restrict__ w1, float* __restrict__ w1T,
                     const float* __restrict__ w2, float* __restrict__ w2T,
                     const float* __restrict__ sup_xyz, int* __restrict__ counts)
{
  int idx = blockIdx.x * 256 + threadIdx.x;
  if (idx < N_SUP) {
    float x = sup_xyz[3*idx], y = sup_xyz[3*idx+1];
    atomicAdd(&counts[binOf(x) * NB + binOf(y)], 1);
  }
  if (idx < CIN * CH1) {
    int k = idx / CH1, t = idx % CH1;
    w1T[idx] = w1[(size_t)t * CIN + k];
  }
  int j = idx - CIN * CH1;
  if (j >= 0 && j < CH1 * CH2) {
    int k = j / CH2, c = j % CH2;
    w2T[j] = w2[(size_t)c * CH1 + k];
  }
}

__global__ void kScan(const int* __restrict__ counts, int* __restrict__ starts, int* __restrict__ cursor)
{
  __shared__ int sc[NB*NB];
  int t = threadIdx.x;
  if (t < NB*NB) sc[t] = counts[t];
  __syncthreads();
  if (t == 0) {
    int acc = 0;
    for (int b = 0; b < NB*NB; b++) { int c = sc[b]; sc[b] = acc; acc += c; }
  }
  __syncthreads();
  if (t < NB*NB) { starts[t] = sc[t]; cursor[t] = sc[t]; }
  if (t == NB*NB) starts[NB*NB] = N_SUP;
}

__global__ void kScatter(const float* __restrict__ sup_xyz, int* __restrict__ cursor,
                         float* __restrict__ xs, float* __restrict__ ys,
                         float* __restrict__ zs, int* __restrict__ sid)
{
  int i = blockIdx.x * 256 + threadIdx.x;
  if (i < N_SUP) {
    float x = sup_xyz[3*i], y = sup_xyz[3*i+1], z = sup_xyz[3*i+2];
    int b = binOf(x) * NB + binOf(y);
    int p = atomicAdd(&cursor[b], 1);
    xs[p] = x; ys[p] = y; zs[p] = z; sid[p] = i;
  }
}

// ---------------- Kernel A12: bin-pruned cube filter + per-voxel 3NN (guarded insert) ----------------
// (round-11 structure: flat scan, no sort/partition — empirically optimal)
__global__ __launch_bounds__(256) void kA12(const float* __restrict__ xs,
                                            const float* __restrict__ ys,
                                            const float* __restrict__ zs,
                                            const int*   __restrict__ sid,
                                            const int*   __restrict__ starts,
                                            const float* __restrict__ new_xyz,
                                            const float* __restrict__ sup_xyz,
                                            float* __restrict__ nnW,
                                            int*   __restrict__ nnGI,
                                            float* __restrict__ nnLX)
{
  __shared__ float4 cxyz[CAP];                 // filtered candidates (.w = sid bits)
  __shared__ unsigned long long sk[TV][8][3];
  __shared__ int s_cnt;

  const int m   = blockIdx.x;
  const int tid = threadIdx.x;
  if (tid == 0) s_cnt = 0;
  __syncthreads();

  const float qx = new_xyz[m*3+0];
  const float qy = new_xyz[m*3+1];
  const float qz = new_xyz[m*3+2];

  // ---- phase 1: cube filter over <=3x3 bins (z-test vacuous: |dz|<4 always) ----
  const int bx0 = binOf(qx - 4.0f), bx1 = binOf(qx + 4.0f);
  const int by0 = binOf(qy - 4.0f), by1 = binOf(qy + 4.0f);
  for (int bx = bx0; bx <= bx1; bx++) {
    const int beg = starts[bx * NB + by0];
    const int end = starts[bx * NB + by1 + 1];
    for (int i = beg + tid; i < end; i += 256) {
      float x = xs[i], y = ys[i];
      if (fabsf(__fsub_rn(x, qx)) <= 4.0f && fabsf(__fsub_rn(y, qy)) <= 4.0f) {
        int p = atomicAdd(&s_cnt, 1);
        if (p < CAP) cxyz[p] = make_float4(x, y, zs[i], __uint_as_float((unsigned)sid[i]));
      }
    }
  }
  __syncthreads();
  const int cnt = (s_cnt < CAP) ? s_cnt : CAP;

  // ---- phase 2a: strided scan, 8 threads per voxel, guarded insert ----
  const int v = tid >> 3, j = tid & 7;
  if (v < TV) {
    const float gx = qx + gsel(v / 9);
    const float gy = qy + gsel((v / 3) % 3);
    const float gz = qz + gsel(v % 3);
    unsigned long long k0 = ~0ull, k1 = ~0ull, k2 = ~0ull;
    float k2df = __uint_as_float(0xFFFFFFFFu);   // NaN sentinel -> insert path until 3 found
    for (int c = j; c < cnt; c += 8) {
      float4 f4 = cxyz[c];
      float dx = __fsub_rn(gx, f4.x);
      float dy = __fsub_rn(gy, f4.y);
      float dz = __fsub_rn(gz, f4.z);
      // forbid FMA contraction: must match numpy f32 (mul, mul, add, mul, add)
      float dd = __fadd_rn(__fadd_rn(__fmul_rn(dx,dx), __fmul_rn(dy,dy)), __fmul_rn(dz,dz));
      if (!(dd > k2df)) {                        // fast reject; == still takes insert (tie by sid)
        unsigned long long key = ((unsigned long long)__float_as_uint(dd) << 32)
                               | (unsigned long long)__float_as_uint(f4.w); // low = sid
        insK(key, k0, k1, k2);
        k2df = __uint_as_float((unsigned)(k2 >> 32));
      }
    }
    sk[v][j][0] = k0; sk[v][j][1] = k1; sk[v][j][2] = k2;
  }
  __syncthreads();

  // ---- phase 2b: merge 8x3 keys per voxel + emit (threads 0..26) ----
  if (tid < TV) {
    const int vv = tid;
    const float gx = qx + gsel(vv / 9);
    const float gy = qy + gsel((vv / 3) % 3);
    const float gz = qz + gsel(vv % 3);
    unsigned long long k0 = ~0ull, k1 = ~0ull, k2 = ~0ull;
    #pragma unroll
    for (int jj = 0; jj < 8; jj++) {
      insK(sk[vv][jj][0], k0, k1, k2);
      insK(sk[vv][jj][1], k0, k1, k2);
      insK(sk[vv][jj][2], k0, k1, k2);
    }
    const int base = m * TV + vv;
    if (cnt > 0) {
      unsigned long long ks[3] = {k0, k1, k2};
      float d[3]; int gi[3]; bool ok[3];
      #pragma unroll
      for (int r = 0; r < 3; r++) {
        unsigned db = (unsigned)(ks[r] >> 32);
        ok[r] = (db != 0xFFFFFFFFu);
        d[r]  = ok[r] ? __uint_as_float(db) : 1e10f;
        gi[r] = ok[r] ? (int)(unsigned)(ks[r] & 0xFFFFFFFFull) : 0;
      }
      float r0 = 1.0f / (d[0] + 1e-8f);
      float r1 = 1.0f / (d[1] + 1e-8f);
      float r2 = 1.0f / (d[2] + 1e-8f);
      float den = fmaxf(r0 + r1 + r2, 1e-8f);
      nnW[base*3+0] = r0 / den; nnW[base*3+1] = r1 / den; nnW[base*3+2] = r2 / den;
      nnGI[base*3+0] = gi[0]; nnGI[base*3+1] = gi[1]; nnGI[base*3+2] = gi[2];
      #pragma unroll
      for (int r = 0; r < 3; r++) {
        if (ok[r]) {
          nnLX[base*9 + r*3 + 0] = gx - sup_xyz[gi[r]*3 + 0];
          nnLX[base*9 + r*3 + 1] = gy - sup_xyz[gi[r]*3 + 1];
          nnLX[base*9 + r*3 + 2] = gz - sup_xyz[gi[r]*3 + 2];
        } else {
          nnLX[base*9 + r*3 + 0] = 0.0f;
          nnLX[base*9 + r*3 + 1] = 0.0f;
          nnLX[base*9 + r*3 + 2] = 0.0f;
        }
      }
    } else {
      #pragma unroll
      for (int r = 0; r < 3; r++) {
        nnW[base*3+r] = 0.0f; nnGI[base*3+r] = 0;
        nnLX[base*9+r*3+0] = 0.0f; nnLX[base*9+r*3+1] = 0.0f; nnLX[base*9+r*3+2] = 0.0f;
      }
    }
  }
}

// ---------------- Kernel A3: interp + grouped conv1 (8 queries/block) + fused BN1 stats ----------------
__global__ __launch_bounds__(256) void kA3(const float* __restrict__ sup_feat,
                                           const float* __restrict__ nnW,
                                           const int*   __restrict__ nnGI,
                                           const float* __restrict__ nnLX,
                                           const float* __restrict__ w1T,
                                           float* __restrict__ y1,
                                           float* __restrict__ stats1)   // [8][2*CH1]
{
  __shared__ float s_feats[8][TV][CIN];
  __shared__ float s_w[8][TV][3];
  __shared__ int   s_gi[8][TV][3];

  const int m0  = blockIdx.x * 8;
  const int tid = threadIdx.x;

  for (int t = tid; t < 8*TV*3; t += 256) {
    int q = t / (TV*3), rem = t % (TV*3);
    s_w[q][rem/3][rem%3]  = nnW[m0*TV*3 + t];
    s_gi[q][rem/3][rem%3] = nnGI[m0*TV*3 + t];
  }
  for (int t = tid; t < 8*TV*9; t += 256) {
    int q = t / (TV*9), rem = t % (TV*9);
    s_feats[q][rem/9][32 + rem%9] = nnLX[m0*TV*9 + t];
  }
  __syncthreads();

  for (int t = tid; t < 8*TV*32; t += 256) {
    const int q = t / (TV*32), rem = t % (TV*32);
    const int v = rem >> 5, ch = rem & 31;
    s_feats[q][v][ch] = s_w[q][v][0] * sup_feat[s_gi[q][v][0]*32 + ch]
                      + s_w[q][v][1] * sup_feat[s_gi[q][v][1]*32 + ch]
                      + s_w[q][v][2] * sup_feat[s_gi[q][v][2]*32 + ch];
  }
  __syncthreads();

  const int copy = (blockIdx.x & 7) * 2 * CH1;   // spread stat atomics over 8 copies
  for (int t = tid; t < CH1; t += 256) {
    const int v = t >> 5;
    float acc[8];
    #pragma unroll
    for (int q = 0; q < 8; q++) acc[q] = 0.0f;
    for (int k = 0; k < CIN; k++) {
      float w = w1T[k * CH1 + t];
      #pragma unroll
      for (int q = 0; q < 8; q++) acc[q] += s_feats[q][v][k] * w;
    }
    float s = 0.0f, ss = 0.0f;
    #pragma unroll
    for (int q = 0; q < 8; q++) {
      y1[(size_t)(m0 + q) * CH1 + t] = acc[q];
      s += acc[q]; ss += acc[q] * acc[q];
    }
    atomicAdd(&stats1[copy + t],       s);
    atomicAdd(&stats1[copy + CH1 + t], ss);
  }
}

// ---------------- Kernel S: BN1 scale/shift precompute (sums 8 stat copies) ----------------
__global__ void kS(const float* __restrict__ stats1,   // [8][2*CH1]
                   const float* __restrict__ g1, const float* __restrict__ b1,
                   float* __restrict__ scsg, float* __restrict__ shsg)
{
  int c = blockIdx.x * 256 + threadIdx.x;
  if (c < CH1) {
    float s = 0.0f, ssq = 0.0f;
    #pragma unroll
    for (int k = 0; k < 8; k++) {
      s   += stats1[k * 2 * CH1 + c];
      ssq += stats1[k * 2 * CH1 + CH1 + c];
    }
    float mu  = s  * (1.0f / M_Q);
    float var = ssq * (1.0f / M_Q) - mu * mu;
    float r   = 1.0f / sqrtf(var + 1e-5f);
    float gg = g1[c];
    scsg[c] = r * gg;
    shsg[c] = b1[c] - mu * r * gg;
  }
}

// ---------------- Kernel C: BN1-fused split-K GEMM, 32x128 tile, 4x4/thread, grid 512 ----------------
__global__ __launch_bounds__(256) void kC(const float* __restrict__ y1,
                                          const float* __restrict__ scsg,
                                          const float* __restrict__ shsg,
                                          const float* __restrict__ w2T,
                                          float* __restrict__ zpart)   // [4][M_Q][CH2]
{
  __shared__ float As[KC_BK][36];      // [k][row], stride 36 (144 B, 16B-aligned rows)
  __shared__ float Bs[KC_BK][CH2];     // 12 KB
  __shared__ float lsc[KC_KS], lsh[KC_KS];

  const int tid = threadIdx.x;
  const int mb  = blockIdx.x & 127;
  const int ch  = blockIdx.x >> 7;
  const int m0  = mb * 32;
  const int kb  = ch * KC_KS;

  for (int t = tid; t < KC_KS; t += 256) { lsc[t] = scsg[kb + t]; lsh[t] = shsg[kb + t]; }

  const int ar = tid >> 3;          // 0..31 A-tile row
  const int ac = (tid & 7) * 3;     // 0..21 A-tile k-offset (3 consecutive)
  const int ty = tid >> 5;          // 0..7  -> rows ty*4..+3
  const int tx = tid & 31;          // 0..31 -> cols tx*4..+3

  // prefetch tile 0
  float pa0, pa1, pa2; float4 pb[3];
  {
    const float* yr = &y1[(size_t)(m0 + ar) * CH1 + kb + ac];
    pa0 = yr[0]; pa1 = yr[1]; pa2 = yr[2];
    #pragma unroll
    for (int jj = 0; jj < 3; jj++) {
      int fid = tid + jj * 256; int kk = fid >> 5, c4 = (fid & 31) * 4;
      pb[jj] = *(const float4*)&w2T[(size_t)(kb + kk) * CH2 + c4];
    }
  }

  float acc[4][4];
  #pragma unroll
  for (int i = 0; i < 4; i++)
    #pragma unroll
    for (int jj = 0; jj < 4; jj++) acc[i][jj] = 0.0f;

  for (int kt = 0; kt < KC_KS / KC_BK; kt++) {
    __syncthreads();                       // previous tile consumed (also covers lsc/lsh at kt=0)
    const int kl = kt * KC_BK + ac;
    As[ac  ][ar] = fmaxf(pa0 * lsc[kl  ] + lsh[kl  ], 0.0f);
    As[ac+1][ar] = fmaxf(pa1 * lsc[kl+1] + lsh[kl+1], 0.0f);
    As[ac+2][ar] = fmaxf(pa2 * lsc[kl+2] + lsh[kl+2], 0.0f);
    #pragma unroll
    for (int jj = 0; jj < 3; jj++) {
      int fid = tid + jj * 256; int kk = fid >> 5, c4 = (fid & 31) * 4;
      *(float4*)&Bs[kk][c4] = pb[jj];
    }
    __syncthreads();
    if (kt + 1 < KC_KS / KC_BK) {          // prefetch next tile (overlaps compute)
      const float* yr = &y1[(size_t)(m0 + ar) * CH1 + kb + (kt+1) * KC_BK + ac];
      pa0 = yr[0]; pa1 = yr[1]; pa2 = yr[2];
      #pragma unroll
      for (int jj = 0; jj < 3; jj++) {
        int fid = tid + jj * 256; int kk = fid >> 5, c4 = (fid & 31) * 4;
        pb[jj] = *(const float4*)&w2T[(size_t)(kb + (kt+1) * KC_BK + kk) * CH2 + c4];
      }
    }
    #pragma unroll
    for (int kk = 0; kk < KC_BK; kk++) {
      float4 av = *(const float4*)&As[kk][ty*4];
      float4 bv = *(const float4*)&Bs[kk][tx*4];
      acc[0][0] += av.x*bv.x; acc[0][1] += av.x*bv.y; acc[0][2] += av.x*bv.z; acc[0][3] += av.x*bv.w;
      acc[1][0] += av.y*bv.x; acc[1][1] += av.y*bv.y; acc[1][2] += av.y*bv.z; acc[1][3] += av.y*bv.w;
      acc[2][0] += av.z*bv.x; acc[2][1] += av.z*bv.y; acc[2][2] += av.z*bv.z; acc[2][3] += av.z*bv.w;
      acc[3][0] += av.w*bv.x; acc[3][1] += av.w*bv.y; acc[3][2] += av.w*bv.z; acc[3][3] += av.w*bv.w;
    }
  }

  float* zp = zpart + (size_t)ch * M_Q * CH2;
  #pragma unroll
  for (int i = 0; i < 4; i++) {
    *(float4*)&zp[(size_t)(m0 + ty*4 + i) * CH2 + tx*4] =
        make_float4(acc[i][0], acc[i][1], acc[i][2], acc[i][3]);
  }
}

// ---------------- Kernel Z: sum split-K partials -> z, BN2 stats ----------------
__global__ void kZ(const float* __restrict__ zpart,
                   float* __restrict__ z,
                   float* __restrict__ stats2)   // [8][256]
{
  const int tid = threadIdx.x;
  const int c = tid & 127, h = tid >> 7;
  const int m0 = blockIdx.x * 64 + h * 32;
  float s = 0.0f, ss = 0.0f;
  for (int r = 0; r < 32; r++) {
    size_t off = (size_t)(m0 + r) * CH2 + c;
    float v = zpart[off]
            + zpart[off + (size_t)M_Q*CH2]
            + zpart[off + (size_t)2*M_Q*CH2]
            + zpart[off + (size_t)3*M_Q*CH2];
    z[off] = v;
    s += v; ss += v * v;
  }
  const int copy = (blockIdx.x & 7) * 256;
  atomicAdd(&stats2[copy + c],       s);
  atomicAdd(&stats2[copy + 128 + c], ss);
}

// ---------------- Kernel D: BN2 apply + ReLU -> f32 out (float4) ----------------
__global__ void kD(const float* __restrict__ z,
                   const float* __restrict__ stats2,   // [8][256]
                   const float* __restrict__ g2,
                   const float* __restrict__ b2,
                   float* __restrict__ out)
{
  int t4 = blockIdx.x * 256 + threadIdx.x;
  if (t4 >= M_Q * CH2 / 4) return;
  int c = (t4 & 31) * 4;
  float4 zv = *(const float4*)&z[(size_t)t4 * 4];
  float4 sv = make_float4(0,0,0,0), qv = make_float4(0,0,0,0);
  #pragma unroll
  for (int k = 0; k < 8; k++) {
    float4 a = *(const float4*)&stats2[k * 256 + c];
    float4 b = *(const float4*)&stats2[k * 256 + 128 + c];
    sv.x += a.x; sv.y += a.y; sv.z += a.z; sv.w += a.w;
    qv.x += b.x; qv.y += b.y; qv.z += b.z; qv.w += b.w;
  }
  float4 gv = *(const float4*)&g2[c];
  float4 bv = *(const float4*)&b2[c];
  float4 o;
  {
    float mu = sv.x * (1.0f/M_Q), var = qv.x * (1.0f/M_Q) - mu*mu;
    o.x = fmaxf((zv.x - mu) * (1.0f/sqrtf(var + 1e-5f)) * gv.x + bv.x, 0.0f);
  }
  {
    float mu = sv.y * (1.0f/M_Q), var = qv.y * (1.0f/M_Q) - mu*mu;
    o.y = fmaxf((zv.y - mu) * (1.0f/sqrtf(var + 1e-5f)) * gv.y + bv.y, 0.0f);
  }
  {
    float mu = sv.z * (1.0f/M_Q), var = qv.z * (1.0f/M_Q) - mu*mu;
    o.z = fmaxf((zv.z - mu) * (1.0f/sqrtf(var + 1e-5f)) * gv.z + bv.z, 0.0f);
  }
  {
    float mu = sv.w * (1.0f/M_Q), var = qv.w * (1.0f/M_Q) - mu*mu;
    o.w = fmaxf((zv.w - mu) * (1.0f/sqrtf(var + 1e-5f)) * gv.w + bv.w, 0.0f);
  }
  *(float4*)&out[(size_t)t4 * 4] = o;
}

extern "C" void kernel_launch(void* const* d_in, const int* in_sizes, int n_in,
                              void* d_out, int out_size, void* d_ws, size_t ws_size,
                              hipStream_t stream)
{
  const float* sup_xyz  = (const float*)d_in[0];
  const float* sup_feat = (const float*)d_in[1];
  const float* new_xyz  = (const float*)d_in[2];
  const float* w1       = (const float*)d_in[3];
  const float* g1       = (const float*)d_in[4];
  const float* b1       = (const float*)d_in[5];
  const float* w2       = (const float*)d_in[6];
  const float* g2       = (const float*)d_in[7];
  const float* b2       = (const float*)d_in[8];
  float* out = (float*)d_out;

  char* ws = (char*)d_ws;
  float* y1     = (float*)(ws);                       // 14,155,776 B
  float* z      = (float*)(ws + 14155776);            //  2,097,152 B (aliased by w1T early)
  float* w2T    = (float*)(ws + 16252928);            //    442,368 B
  float* stats1 = (float*)(ws + 16695296);            // 8 x 1728 f32 = 55,296 B
  float* stats2 = (float*)(ws + 16750592);            // 8 x  256 f32 =  8,192 B
  int*   counts = (int*)  (ws + 16758784);            //        576 B
  int*   cursor = (int*)  (ws + 16759360);            //        576 B
  int*   starts = (int*)  (ws + 16759936);            //        580 B
  float* xs     = (float*)(ws + 16760516);            //     65,536 B
  float* ys     = (float*)(ws + 16826052);
  float* zs     = (float*)(ws + 16891588);
  int*   sid    = (int*)  (ws + 16957124);
  float* nnW    = (float*)(ws + 17022660);            //  1,327,104 B
  int*   nnGI   = (int*)  (ws + 18349764);            //  1,327,104 B
  float* nnLX   = (float*)(ws + 19676868);            //  3,981,312 B
  // zpart (4 x 2,097,152 B = 8,388,608 B) aliases nnW/nnGI/nnLX (dead after kA3)
  // and extends past them; total ws footprint = 17,022,660 + 8,388,608 = 25,411,268 B.
  float* zpart  = (float*)(ws + 17022660);
  // w1T (141,696 B) aliases z: kA3 (last reader) runs before kC/kZ touch z.
  float* w1T    = z;
  // scsg/shsg (3456 B each) alias xs/ys: dead after kA12; kS rewrites before kC reads.
  float* scsg   = xs;
  float* shsg   = ys;

  // zero stats1 + stats2 + counts + cursor in one contiguous memset
  hipMemsetAsync(stats1, 0, 55296 + 8192 + 576 + 576, stream);

  const int PRE_TOT = CIN*CH1 + CH1*CH2;              // covers N_SUP too
  hipLaunchKernelGGL(kPre,    dim3((PRE_TOT + 255) / 256), dim3(256), 0, stream, w1, w1T, w2, w2T, sup_xyz, counts);
  hipLaunchKernelGGL(kScan,   dim3(1),                    dim3(256), 0, stream, counts, starts, cursor);
  hipLaunchKernelGGL(kScatter,dim3((N_SUP + 255) / 256),  dim3(256), 0, stream, sup_xyz, cursor, xs, ys, zs, sid);
  hipLaunchKernelGGL(kA12,    dim3(M_Q),                  dim3(256), 0, stream, xs, ys, zs, sid, starts, new_xyz, sup_xyz, nnW, nnGI, nnLX);
  hipLaunchKernelGGL(kA3,     dim3(M_Q / 8),              dim3(256), 0, stream, sup_feat, nnW, nnGI, nnLX, w1T, y1, stats1);
  hipLaunchKernelGGL(kS,      dim3((CH1 + 255) / 256),    dim3(256), 0, stream, stats1, g1, b1, scsg, shsg);
  hipLaunchKernelGGL(kC,      dim3(128 * KC_NCH),         dim3(256), 0, stream, y1, scsg, shsg, w2T, zpart);
  hipLaunchKernelGGL(kZ,      dim3(M_Q / 64),             dim3(256), 0, stream, zpart, z, stats2);
  hipLaunchKernelGGL(kD,      dim3(M_Q * CH2 / 4 / 256),  dim3(256), 0, stream, z, stats2, g2, b2, out);
}

// Round 16
// 144.895 us; speedup vs baseline: 1.2383x; 1.0384x over previous
//
#include <hip/hip_runtime.h>
#include <hip/hip_bf16.h>

#define N_SUP 16384
#define M_Q   4096
#define TV    27
#define CIN   41
#define CH1   864
#define CH2   128
#define CAP   1024
#define NB    12          // bins per xy axis (width 50/12 = 4.17 >= 4)

// kC split-K tiling: 32x128 tile, 4x4/thread, BK=24, 4 K-chunks of 216 -> grid 512
#define KC_BK  24
#define KC_KS  216
#define KC_NCH 4

// grid offset value for axis-index 0/1/2 : linspace(-R+R/NV, R-R/NV, 3) = {-1.3333334, 0, +1.3333334}
__device__ __forceinline__ float gsel(int i){
  const float GOFF = (float)(-2.0 + 2.0 / 3.0);   // -1.3333334f (matches f32 linspace endpoint)
  return (i == 0) ? GOFF : ((i == 2) ? -GOFF : 0.0f);
}

__device__ __forceinline__ int binOf(float x){
  int b = (int)(x * (float)(NB / 50.0));
  return (b < 0) ? 0 : ((b > NB - 1) ? NB - 1 : b);
}

// branchless 3-deep insert of u64 key (keeps k0 <= k1 <= k2)
__device__ __forceinline__ void insK(unsigned long long key,
                                     unsigned long long& k0,
                                     unsigned long long& k1,
                                     unsigned long long& k2){
  bool b0 = key < k0, b1 = key < k1, b2 = key < k2;
  k2 = b1 ? k1 : (b2 ? key : k2);
  k1 = b0 ? k0 : (b1 ? key : k1);
  k0 = b0 ? key : k0;
}

// ---------------- Kernel Pre: w1/w2 transpose + support-point bin count (fused) ----------------
__global__ void kPre(const float* __restrict__ w1, float* __restrict__ w1T,
                     const float* __restrict__ w2, float* __restrict__ w2T,
                     const float* __restrict__ sup_xyz, int* __restrict__ counts)
{
  int idx = blockIdx.x * 256 + threadIdx.x;
  if (idx < N_SUP) {
    float x = sup_xyz[3*idx], y = sup_xyz[3*idx+1];
    atomicAdd(&counts[binOf(x) * NB + binOf(y)], 1);
  }
  if (idx < CIN * CH1) {
    int k = idx / CH1, t = idx % CH1;
    w1T[idx] = w1[(size_t)t * CIN + k];
  }
  int j = idx - CIN * CH1;
  if (j >= 0 && j < CH1 * CH2) {
    int k = j / CH2, c = j % CH2;
    w2T[j] = w2[(size_t)c * CH1 + k];
  }
}

__global__ void kScan(const int* __restrict__ counts, int* __restrict__ starts, int* __restrict__ cursor)
{
  __shared__ int sc[NB*NB];
  int t = threadIdx.x;
  if (t < NB*NB) sc[t] = counts[t];
  __syncthreads();
  if (t == 0) {
    int acc = 0;
    for (int b = 0; b < NB*NB; b++) { int c = sc[b]; sc[b] = acc; acc += c; }
  }
  __syncthreads();
  if (t < NB*NB) { starts[t] = sc[t]; cursor[t] = sc[t]; }
  if (t == NB*NB) starts[NB*NB] = N_SUP;
}

__global__ void kScatter(const float* __restrict__ sup_xyz, int* __restrict__ cursor,
                         float* __restrict__ xs, float* __restrict__ ys,
                         float* __restrict__ zs, int* __restrict__ sid)
{
  int i = blockIdx.x * 256 + threadIdx.x;
  if (i < N_SUP) {
    float x = sup_xyz[3*i], y = sup_xyz[3*i+1], z = sup_xyz[3*i+2];
    int b = binOf(x) * NB + binOf(y);
    int p = atomicAdd(&cursor[b], 1);
    xs[p] = x; ys[p] = y; zs[p] = z; sid[p] = i;
  }
}

// ---------------- Kernel A12: bin-pruned cube filter + per-voxel 3NN (guarded insert) ----------------
// (round-11 structure: flat scan; emit reduced to (d,gi) dump — weights/local_xyz moved to kA3)
__global__ __launch_bounds__(256) void kA12(const float* __restrict__ xs,
                                            const float* __restrict__ ys,
                                            const float* __restrict__ zs,
                                            const int*   __restrict__ sid,
                                            const int*   __restrict__ starts,
                                            const float* __restrict__ new_xyz,
                                            float* __restrict__ nnD,
                                            int*   __restrict__ nnGI)
{
  __shared__ float4 cxyz[CAP];                 // filtered candidates (.w = sid bits)
  __shared__ unsigned long long sk[TV][8][3];
  __shared__ int s_cnt;

  const int m   = blockIdx.x;
  const int tid = threadIdx.x;
  if (tid == 0) s_cnt = 0;
  __syncthreads();

  const float qx = new_xyz[m*3+0];
  const float qy = new_xyz[m*3+1];
  const float qz = new_xyz[m*3+2];

  // ---- phase 1: cube filter over <=3x3 bins (z-test vacuous: |dz|<4 always) ----
  const int bx0 = binOf(qx - 4.0f), bx1 = binOf(qx + 4.0f);
  const int by0 = binOf(qy - 4.0f), by1 = binOf(qy + 4.0f);
  for (int bx = bx0; bx <= bx1; bx++) {
    const int beg = starts[bx * NB + by0];
    const int end = starts[bx * NB + by1 + 1];
    for (int i = beg + tid; i < end; i += 256) {
      float x = xs[i], y = ys[i];
      if (fabsf(__fsub_rn(x, qx)) <= 4.0f && fabsf(__fsub_rn(y, qy)) <= 4.0f) {
        int p = atomicAdd(&s_cnt, 1);
        if (p < CAP) cxyz[p] = make_float4(x, y, zs[i], __uint_as_float((unsigned)sid[i]));
      }
    }
  }
  __syncthreads();
  const int cnt = (s_cnt < CAP) ? s_cnt : CAP;

  // ---- phase 2a: strided scan, 8 threads per voxel, guarded insert ----
  const int v = tid >> 3, j = tid & 7;
  if (v < TV) {
    const float gx = qx + gsel(v / 9);
    const float gy = qy + gsel((v / 3) % 3);
    const float gz = qz + gsel(v % 3);
    unsigned long long k0 = ~0ull, k1 = ~0ull, k2 = ~0ull;
    float k2df = __uint_as_float(0xFFFFFFFFu);   // NaN sentinel -> insert path until 3 found
    for (int c = j; c < cnt; c += 8) {
      float4 f4 = cxyz[c];
      float dx = __fsub_rn(gx, f4.x);
      float dy = __fsub_rn(gy, f4.y);
      float dz = __fsub_rn(gz, f4.z);
      // forbid FMA contraction: must match numpy f32 (mul, mul, add, mul, add)
      float dd = __fadd_rn(__fadd_rn(__fmul_rn(dx,dx), __fmul_rn(dy,dy)), __fmul_rn(dz,dz));
      if (!(dd > k2df)) {                        // fast reject; == still takes insert (tie by sid)
        unsigned long long key = ((unsigned long long)__float_as_uint(dd) << 32)
                               | (unsigned long long)__float_as_uint(f4.w); // low = sid
        insK(key, k0, k1, k2);
        k2df = __uint_as_float((unsigned)(k2 >> 32));
      }
    }
    sk[v][j][0] = k0; sk[v][j][1] = k1; sk[v][j][2] = k2;
  }
  __syncthreads();

  // ---- phase 2b: merge 8x3 keys per voxel + dump (d,gi) (threads 0..26) ----
  if (tid < TV) {
    const int vv = tid;
    unsigned long long k0 = ~0ull, k1 = ~0ull, k2 = ~0ull;
    #pragma unroll
    for (int jj = 0; jj < 8; jj++) {
      insK(sk[vv][jj][0], k0, k1, k2);
      insK(sk[vv][jj][1], k0, k1, k2);
      insK(sk[vv][jj][2], k0, k1, k2);
    }
    const int base = m * TV + vv;
    if (cnt > 0) {
      unsigned long long ks[3] = {k0, k1, k2};
      #pragma unroll
      for (int r = 0; r < 3; r++) {
        unsigned db = (unsigned)(ks[r] >> 32);
        bool ok = (db != 0xFFFFFFFFu);
        nnD[base*3+r]  = ok ? __uint_as_float(db) : 1e10f;
        nnGI[base*3+r] = ok ? (int)(unsigned)(ks[r] & 0xFFFFFFFFull) : 0;
      }
    } else {
      #pragma unroll
      for (int r = 0; r < 3; r++) { nnD[base*3+r] = -1.0f; nnGI[base*3+r] = 0; }
    }
  }
}

// ---------------- Kernel A3: weights + local_xyz + interp + conv1 (4 queries/block) + BN1 stats ----------------
__global__ __launch_bounds__(256) void kA3(const float* __restrict__ sup_feat,
                                           const float* __restrict__ sup_xyz,
                                           const float* __restrict__ new_xyz,
                                           const float* __restrict__ nnD,
                                           const int*   __restrict__ nnGI,
                                           const float* __restrict__ w1T,
                                           float* __restrict__ y1,
                                           float* __restrict__ stats1)   // [8][2*CH1]
{
  __shared__ float s_feats[4][TV][CIN];   // 17,712 B
  __shared__ float s_w[4][TV][3];
  __shared__ int   s_gi[4][TV][3];

  const int m0  = blockIdx.x * 4;
  const int tid = threadIdx.x;

  // per-(q,v) thread: weights + local_xyz (108 threads)
  if (tid < 4*TV) {
    const int q = tid / TV, vv = tid % TV;
    const int m = m0 + q;
    const int base = m * TV + vv;
    float d[3]; int gi[3];
    #pragma unroll
    for (int r = 0; r < 3; r++) { d[r] = nnD[base*3+r]; gi[r] = nnGI[base*3+r]; }
    #pragma unroll
    for (int r = 0; r < 3; r++) s_gi[q][vv][r] = gi[r];
    if (d[0] < 0.0f) {                           // empty query: zero weights + zero local
      #pragma unroll
      for (int r = 0; r < 3; r++) s_w[q][vv][r] = 0.0f;
      #pragma unroll
      for (int jj = 0; jj < 9; jj++) s_feats[q][vv][32 + jj] = 0.0f;
    } else {
      float r0 = 1.0f / (d[0] + 1e-8f);
      float r1 = 1.0f / (d[1] + 1e-8f);
      float r2 = 1.0f / (d[2] + 1e-8f);
      float den = fmaxf(r0 + r1 + r2, 1e-8f);
      s_w[q][vv][0] = r0 / den; s_w[q][vv][1] = r1 / den; s_w[q][vv][2] = r2 / den;
      const float gx = new_xyz[m*3+0] + gsel(vv / 9);
      const float gy = new_xyz[m*3+1] + gsel((vv / 3) % 3);
      const float gz = new_xyz[m*3+2] + gsel(vv % 3);
      #pragma unroll
      for (int r = 0; r < 3; r++) {
        bool ok = (d[r] != 1e10f);
        s_feats[q][vv][32 + r*3 + 0] = ok ? (gx - sup_xyz[gi[r]*3 + 0]) : 0.0f;
        s_feats[q][vv][32 + r*3 + 1] = ok ? (gy - sup_xyz[gi[r]*3 + 1]) : 0.0f;
        s_feats[q][vv][32 + r*3 + 2] = ok ? (gz - sup_xyz[gi[r]*3 + 2]) : 0.0f;
      }
    }
  }
  __syncthreads();

  // interp: 4*27*32 = 3456 elements
  for (int t = tid; t < 4*TV*32; t += 256) {
    const int q = t / (TV*32), rem = t % (TV*32);
    const int v = rem >> 5, ch = rem & 31;
    s_feats[q][v][ch] = s_w[q][v][0] * sup_feat[s_gi[q][v][0]*32 + ch]
                      + s_w[q][v][1] * sup_feat[s_gi[q][v][1]*32 + ch]
                      + s_w[q][v][2] * sup_feat[s_gi[q][v][2]*32 + ch];
  }
  __syncthreads();

  const int copy = (blockIdx.x & 7) * 2 * CH1;   // spread stat atomics over 8 copies
  for (int t = tid; t < CH1; t += 256) {
    const int v = t >> 5;
    float acc[4];
    #pragma unroll
    for (int q = 0; q < 4; q++) acc[q] = 0.0f;
    for (int k = 0; k < CIN; k++) {
      float w = w1T[k * CH1 + t];
      #pragma unroll
      for (int q = 0; q < 4; q++) acc[q] += s_feats[q][v][k] * w;
    }
    float s = 0.0f, ss = 0.0f;
    #pragma unroll
    for (int q = 0; q < 4; q++) {
      y1[(size_t)(m0 + q) * CH1 + t] = acc[q];
      s += acc[q]; ss += acc[q] * acc[q];
    }
    atomicAdd(&stats1[copy + t],       s);
    atomicAdd(&stats1[copy + CH1 + t], ss);
  }
}

// ---------------- Kernel C: BN1-fused split-K GEMM (kS fused), 32x128 tile, 4x4/thread, grid 512 ----------------
__global__ __launch_bounds__(256) void kC(const float* __restrict__ y1,
                                          const float* __restrict__ stats1,   // [8][2*CH1]
                                          const float* __restrict__ g1,
                                          const float* __restrict__ b1,
                                          const float* __restrict__ w2T,
                                          float* __restrict__ zpart)   // [4][M_Q][CH2]
{
  __shared__ float As[KC_BK][36];      // [k][row], stride 36 (144 B, 16B-aligned rows)
  __shared__ float Bs[KC_BK][CH2];     // 12 KB
  __shared__ float lsc[KC_KS], lsh[KC_KS];

  const int tid = threadIdx.x;
  const int mb  = blockIdx.x & 127;
  const int ch  = blockIdx.x >> 7;
  const int m0  = mb * 32;
  const int kb  = ch * KC_KS;

  // fused kS: BN1 scale/shift for this chunk's 216 channels (sums 8 stat copies)
  for (int t = tid; t < KC_KS; t += 256) {
    const int c = kb + t;
    float s = 0.0f, ssq = 0.0f;
    #pragma unroll
    for (int k = 0; k < 8; k++) {
      s   += stats1[k * 2 * CH1 + c];
      ssq += stats1[k * 2 * CH1 + CH1 + c];
    }
    float mu  = s  * (1.0f / M_Q);
    float var = ssq * (1.0f / M_Q) - mu * mu;
    float r   = 1.0f / sqrtf(var + 1e-5f);
    float gg = g1[c];
    lsc[t] = r * gg;
    lsh[t] = b1[c] - mu * r * gg;
  }

  const int ar = tid >> 3;          // 0..31 A-tile row
  const int ac = (tid & 7) * 3;     // 0..21 A-tile k-offset (3 consecutive)
  const int ty = tid >> 5;          // 0..7  -> rows ty*4..+3
  const int tx = tid & 31;          // 0..31 -> cols tx*4..+3

  // prefetch tile 0
  float pa0, pa1, pa2; float4 pb[3];
  {
    const float* yr = &y1[(size_t)(m0 + ar) * CH1 + kb + ac];
    pa0 = yr[0]; pa1 = yr[1]; pa2 = yr[2];
    #pragma unroll
    for (int jj = 0; jj < 3; jj++) {
      int fid = tid + jj * 256; int kk = fid >> 5, c4 = (fid & 31) * 4;
      pb[jj] = *(const float4*)&w2T[(size_t)(kb + kk) * CH2 + c4];
    }
  }

  float acc[4][4];
  #pragma unroll
  for (int i = 0; i < 4; i++)
    #pragma unroll
    for (int jj = 0; jj < 4; jj++) acc[i][jj] = 0.0f;

  for (int kt = 0; kt < KC_KS / KC_BK; kt++) {
    __syncthreads();                       // previous tile consumed; covers lsc/lsh at kt=0
    const int kl = kt * KC_BK + ac;
    As[ac  ][ar] = fmaxf(pa0 * lsc[kl  ] + lsh[kl  ], 0.0f);
    As[ac+1][ar] = fmaxf(pa1 * lsc[kl+1] + lsh[kl+1], 0.0f);
    As[ac+2][ar] = fmaxf(pa2 * lsc[kl+2] + lsh[kl+2], 0.0f);
    #pragma unroll
    for (int jj = 0; jj < 3; jj++) {
      int fid = tid + jj * 256; int kk = fid >> 5, c4 = (fid & 31) * 4;
      *(float4*)&Bs[kk][c4] = pb[jj];
    }
    __syncthreads();
    if (kt + 1 < KC_KS / KC_BK) {          // prefetch next tile (overlaps compute)
      const float* yr = &y1[(size_t)(m0 + ar) * CH1 + kb + (kt+1) * KC_BK + ac];
      pa0 = yr[0]; pa1 = yr[1]; pa2 = yr[2];
      #pragma unroll
      for (int jj = 0; jj < 3; jj++) {
        int fid = tid + jj * 256; int kk = fid >> 5, c4 = (fid & 31) * 4;
        pb[jj] = *(const float4*)&w2T[(size_t)(kb + (kt+1) * KC_BK + kk) * CH2 + c4];
      }
    }
    #pragma unroll
    for (int kk = 0; kk < KC_BK; kk++) {
      float4 av = *(const float4*)&As[kk][ty*4];
      float4 bv = *(const float4*)&Bs[kk][tx*4];
      acc[0][0] += av.x*bv.x; acc[0][1] += av.x*bv.y; acc[0][2] += av.x*bv.z; acc[0][3] += av.x*bv.w;
      acc[1][0] += av.y*bv.x; acc[1][1] += av.y*bv.y; acc[1][2] += av.y*bv.z; acc[1][3] += av.y*bv.w;
      acc[2][0] += av.z*bv.x; acc[2][1] += av.z*bv.y; acc[2][2] += av.z*bv.z; acc[2][3] += av.z*bv.w;
      acc[3][0] += av.w*bv.x; acc[3][1] += av.w*bv.y; acc[3][2] += av.w*bv.z; acc[3][3] += av.w*bv.w;
    }
  }

  float* zp = zpart + (size_t)ch * M_Q * CH2;
  #pragma unroll
  for (int i = 0; i < 4; i++) {
    *(float4*)&zp[(size_t)(m0 + ty*4 + i) * CH2 + tx*4] =
        make_float4(acc[i][0], acc[i][1], acc[i][2], acc[i][3]);
  }
}

// ---------------- Kernel Z: sum split-K partials -> z, BN2 stats (grid 512) ----------------
__global__ void kZ(const float* __restrict__ zpart,
                   float* __restrict__ z,
                   float* __restrict__ stats2)   // [8][256]
{
  const int tid = threadIdx.x;
  const int c = tid & 127, h = tid >> 7;
  const int m0 = blockIdx.x * 8 + h * 4;
  float s = 0.0f, ss = 0.0f;
  for (int r = 0; r < 4; r++) {
    size_t off = (size_t)(m0 + r) * CH2 + c;
    float v = zpart[off]
            + zpart[off + (size_t)M_Q*CH2]
            + zpart[off + (size_t)2*M_Q*CH2]
            + zpart[off + (size_t)3*M_Q*CH2];
    z[off] = v;
    s += v; ss += v * v;
  }
  const int copy = (blockIdx.x & 7) * 256;
  atomicAdd(&stats2[copy + c],       s);
  atomicAdd(&stats2[copy + 128 + c], ss);
}

// ---------------- Kernel D: BN2 apply + ReLU -> f32 out (float4) ----------------
__global__ void kD(const float* __restrict__ z,
                   const float* __restrict__ stats2,   // [8][256]
                   const float* __restrict__ g2,
                   const float* __restrict__ b2,
                   float* __restrict__ out)
{
  int t4 = blockIdx.x * 256 + threadIdx.x;
  if (t4 >= M_Q * CH2 / 4) return;
  int c = (t4 & 31) * 4;
  float4 zv = *(const float4*)&z[(size_t)t4 * 4];
  float4 sv = make_float4(0,0,0,0), qv = make_float4(0,0,0,0);
  #pragma unroll
  for (int k = 0; k < 8; k++) {
    float4 a = *(const float4*)&stats2[k * 256 + c];
    float4 b = *(const float4*)&stats2[k * 256 + 128 + c];
    sv.x += a.x; sv.y += a.y; sv.z += a.z; sv.w += a.w;
    qv.x += b.x; qv.y += b.y; qv.z += b.z; qv.w += b.w;
  }
  float4 gv = *(const float4*)&g2[c];
  float4 bv = *(const float4*)&b2[c];
  float4 o;
  {
    float mu = sv.x * (1.0f/M_Q), var = qv.x * (1.0f/M_Q) - mu*mu;
    o.x = fmaxf((zv.x - mu) * (1.0f/sqrtf(var + 1e-5f)) * gv.x + bv.x, 0.0f);
  }
  {
    float mu = sv.y * (1.0f/M_Q), var = qv.y * (1.0f/M_Q) - mu*mu;
    o.y = fmaxf((zv.y - mu) * (1.0f/sqrtf(var + 1e-5f)) * gv.y + bv.y, 0.0f);
  }
  {
    float mu = sv.z * (1.0f/M_Q), var = qv.z * (1.0f/M_Q) - mu*mu;
    o.z = fmaxf((zv.z - mu) * (1.0f/sqrtf(var + 1e-5f)) * gv.z + bv.z, 0.0f);
  }
  {
    float mu = sv.w * (1.0f/M_Q), var = qv.w * (1.0f/M_Q) - mu*mu;
    o.w = fmaxf((zv.w - mu) * (1.0f/sqrtf(var + 1e-5f)) * gv.w + bv.w, 0.0f);
  }
  *(float4*)&out[(size_t)t4 * 4] = o;
}

extern "C" void kernel_launch(void* const* d_in, const int* in_sizes, int n_in,
                              void* d_out, int out_size, void* d_ws, size_t ws_size,
                              hipStream_t stream)
{
  const float* sup_xyz  = (const float*)d_in[0];
  const float* sup_feat = (const float*)d_in[1];
  const float* new_xyz  = (const float*)d_in[2];
  const float* w1       = (const float*)d_in[3];
  const float* g1       = (const float*)d_in[4];
  const float* b1       = (const float*)d_in[5];
  const float* w2       = (const float*)d_in[6];
  const float* g2       = (const float*)d_in[7];
  const float* b2       = (const float*)d_in[8];
  float* out = (float*)d_out;

  char* ws = (char*)d_ws;
  float* y1     = (float*)(ws);                       // 14,155,776 B
  float* z      = (float*)(ws + 14155776);            //  2,097,152 B (aliased by w1T early)
  float* w2T    = (float*)(ws + 16252928);            //    442,368 B
  float* stats1 = (float*)(ws + 16695296);            // 8 x 1728 f32 = 55,296 B
  float* stats2 = (float*)(ws + 16750592);            // 8 x  256 f32 =  8,192 B
  int*   counts = (int*)  (ws + 16758784);            //        576 B
  int*   cursor = (int*)  (ws + 16759360);            //        576 B
  int*   starts = (int*)  (ws + 16759936);            //        580 B
  float* xs     = (float*)(ws + 16760516);            //     65,536 B
  float* ys     = (float*)(ws + 16826052);
  float* zs     = (float*)(ws + 16891588);
  int*   sid    = (int*)  (ws + 16957124);
  float* nnD    = (float*)(ws + 17022660);            //  1,327,104 B
  int*   nnGI   = (int*)  (ws + 18349764);            //  1,327,104 B
  // zpart (4 x 2,097,152 B = 8,388,608 B) aliases nnD/nnGI (dead after kA3) and
  // extends past them; total ws footprint = 17,022,660 + 8,388,608 = 25,411,268 B.
  float* zpart  = (float*)(ws + 17022660);
  // w1T (141,696 B) aliases z: kA3 (last reader) runs before kC/kZ touch z.
  float* w1T    = z;

  // zero stats1 + stats2 + counts + cursor in one contiguous memset
  hipMemsetAsync(stats1, 0, 55296 + 8192 + 576 + 576, stream);

  const int PRE_TOT = CIN*CH1 + CH1*CH2;              // covers N_SUP too
  hipLaunchKernelGGL(kPre,    dim3((PRE_TOT + 255) / 256), dim3(256), 0, stream, w1, w1T, w2, w2T, sup_xyz, counts);
  hipLaunchKernelGGL(kScan,   dim3(1),                    dim3(256), 0, stream, counts, starts, cursor);
  hipLaunchKernelGGL(kScatter,dim3((N_SUP + 255) / 256),  dim3(256), 0, stream, sup_xyz, cursor, xs, ys, zs, sid);
  hipLaunchKernelGGL(kA12,    dim3(M_Q),                  dim3(256), 0, stream, xs, ys, zs, sid, starts, new_xyz, nnD, nnGI);
  hipLaunchKernelGGL(kA3,     dim3(M_Q / 4),              dim3(256), 0, stream, sup_feat, sup_xyz, new_xyz, nnD, nnGI, w1T, y1, stats1);
  hipLaunchKernelGGL(kC,      dim3(128 * KC_NCH),         dim3(256), 0, stream, y1, stats1, g1, b1, w2T, zpart);
  hipLaunchKernelGGL(kZ,      dim3(M_Q / 8),              dim3(256), 0, stream, zpart, z, stats2);
  hipLaunchKernelGGL(kD,      dim3(M_Q * CH2 / 4 / 256),  dim3(256), 0, stream, z, stats2, g2, b2, out);
}

// Round 17
// 140.112 us; speedup vs baseline: 1.2806x; 1.0341x over previous
//
#include <hip/hip_runtime.h>
#include <hip/hip_bf16.h>

#define N_SUP 16384
#define M_Q   4096
#define TV    27
#define CIN   41
#define CH1   864
#define CH2   128
#define CAP   1024
#define NB    12          // bins per xy axis (width 50/12 = 4.17 >= 4)
#define NSL   9           // candidate-scan slices per voxel (27*9 = 243 threads)

// kC split-K tiling: 32x128 tile, 4x4/thread, BK=24, 4 K-chunks of 216 -> grid 512
#define KC_BK  24
#define KC_KS  216
#define KC_NCH 4

// grid offset value for axis-index 0/1/2 : linspace(-R+R/NV, R-R/NV, 3) = {-1.3333334, 0, +1.3333334}
__device__ __forceinline__ float gsel(int i){
  const float GOFF = (float)(-2.0 + 2.0 / 3.0);   // -1.3333334f (matches f32 linspace endpoint)
  return (i == 0) ? GOFF : ((i == 2) ? -GOFF : 0.0f);
}

__device__ __forceinline__ int binOf(float x){
  int b = (int)(x * (float)(NB / 50.0));
  return (b < 0) ? 0 : ((b > NB - 1) ? NB - 1 : b);
}

// branchless 3-deep insert of u64 key (keeps k0 <= k1 <= k2)
__device__ __forceinline__ void insK(unsigned long long key,
                                     unsigned long long& k0,
                                     unsigned long long& k1,
                                     unsigned long long& k2){
  bool b0 = key < k0, b1 = key < k1, b2 = key < k2;
  k2 = b1 ? k1 : (b2 ? key : k2);
  k1 = b0 ? k0 : (b1 ? key : k1);
  k0 = b0 ? key : k0;
}

// ---------------- Kernel Pre: w1/w2 transpose + support-point bin count (fused) ----------------
__global__ void kPre(const float* __restrict__ w1, float* __restrict__ w1T,
                     const float* __restrict__ w2, float* __restrict__ w2T,
                     const float* __restrict__ sup_xyz, int* __restrict__ counts)
{
  int idx = blockIdx.x * 256 + threadIdx.x;
  if (idx < N_SUP) {
    float x = sup_xyz[3*idx], y = sup_xyz[3*idx+1];
    atomicAdd(&counts[binOf(x) * NB + binOf(y)], 1);
  }
  if (idx < CIN * CH1) {
    int k = idx / CH1, t = idx % CH1;
    w1T[idx] = w1[(size_t)t * CIN + k];
  }
  int j = idx - CIN * CH1;
  if (j >= 0 && j < CH1 * CH2) {
    int k = j / CH2, c = j % CH2;
    w2T[j] = w2[(size_t)c * CH1 + k];
  }
}

__global__ void kScan(const int* __restrict__ counts, int* __restrict__ starts, int* __restrict__ cursor)
{
  __shared__ int sc[NB*NB];
  int t = threadIdx.x;
  if (t < NB*NB) sc[t] = counts[t];
  __syncthreads();
  if (t == 0) {
    int acc = 0;
    for (int b = 0; b < NB*NB; b++) { int c = sc[b]; sc[b] = acc; acc += c; }
  }
  __syncthreads();
  if (t < NB*NB) { starts[t] = sc[t]; cursor[t] = sc[t]; }
  if (t == NB*NB) starts[NB*NB] = N_SUP;
}

__global__ void kScatter(const float* __restrict__ sup_xyz, int* __restrict__ cursor,
                         float4* __restrict__ pxyzs)
{
  int i = blockIdx.x * 256 + threadIdx.x;
  if (i < N_SUP) {
    float x = sup_xyz[3*i], y = sup_xyz[3*i+1], z = sup_xyz[3*i+2];
    int b = binOf(x) * NB + binOf(y);
    int p = atomicAdd(&cursor[b], 1);
    pxyzs[p] = make_float4(x, y, z, __uint_as_float((unsigned)i));
  }
}

// ---------------- Kernel A12: bin-pruned cube filter + per-voxel 3NN (guarded insert) ----------------
// (round-11 flat-scan structure; 9 slices/voxel; packed float4 point loads)
__global__ __launch_bounds__(256) void kA12(const float4* __restrict__ pxyzs,
                                            const int*   __restrict__ starts,
                                            const float* __restrict__ new_xyz,
                                            float* __restrict__ nnD,
                                            int*   __restrict__ nnGI)
{
  __shared__ float4 cxyz[CAP];                 // filtered candidates (.w = sid bits)
  __shared__ unsigned long long sk[TV][NSL][3];
  __shared__ int s_cnt;

  const int m   = blockIdx.x;
  const int tid = threadIdx.x;
  if (tid == 0) s_cnt = 0;
  __syncthreads();

  const float qx = new_xyz[m*3+0];
  const float qy = new_xyz[m*3+1];
  const float qz = new_xyz[m*3+2];

  // ---- phase 1: cube filter over <=3x3 bins (z-test vacuous: |dz|<4 always) ----
  const int bx0 = binOf(qx - 4.0f), bx1 = binOf(qx + 4.0f);
  const int by0 = binOf(qy - 4.0f), by1 = binOf(qy + 4.0f);
  for (int bx = bx0; bx <= bx1; bx++) {
    const int beg = starts[bx * NB + by0];
    const int end = starts[bx * NB + by1 + 1];
    for (int i = beg + tid; i < end; i += 256) {
      float4 pt = pxyzs[i];
      if (fabsf(__fsub_rn(pt.x, qx)) <= 4.0f && fabsf(__fsub_rn(pt.y, qy)) <= 4.0f) {
        int p = atomicAdd(&s_cnt, 1);
        if (p < CAP) cxyz[p] = pt;
      }
    }
  }
  __syncthreads();
  const int cnt = (s_cnt < CAP) ? s_cnt : CAP;

  // ---- phase 2a: strided scan, 9 threads per voxel, guarded insert ----
  const int v = tid / NSL, j = tid % NSL;      // 243 active threads
  if (v < TV) {
    const float gx = qx + gsel(v / 9);
    const float gy = qy + gsel((v / 3) % 3);
    const float gz = qz + gsel(v % 3);
    unsigned long long k0 = ~0ull, k1 = ~0ull, k2 = ~0ull;
    float k2df = __uint_as_float(0xFFFFFFFFu);   // NaN sentinel -> insert path until 3 found
    for (int c = j; c < cnt; c += NSL) {
      float4 f4 = cxyz[c];
      float dx = __fsub_rn(gx, f4.x);
      float dy = __fsub_rn(gy, f4.y);
      float dz = __fsub_rn(gz, f4.z);
      // forbid FMA contraction: must match numpy f32 (mul, mul, add, mul, add)
      float dd = __fadd_rn(__fadd_rn(__fmul_rn(dx,dx), __fmul_rn(dy,dy)), __fmul_rn(dz,dz));
      if (!(dd > k2df)) {                        // fast reject; == still takes insert (tie by sid)
        unsigned long long key = ((unsigned long long)__float_as_uint(dd) << 32)
                               | (unsigned long long)__float_as_uint(f4.w); // low = sid
        insK(key, k0, k1, k2);
        k2df = __uint_as_float((unsigned)(k2 >> 32));
      }
    }
    sk[v][j][0] = k0; sk[v][j][1] = k1; sk[v][j][2] = k2;
  }
  __syncthreads();

  // ---- phase 2b: merge 9x3 keys per voxel + dump (d,gi) (threads 0..26) ----
  if (tid < TV) {
    const int vv = tid;
    unsigned long long k0 = ~0ull, k1 = ~0ull, k2 = ~0ull;
    #pragma unroll
    for (int jj = 0; jj < NSL; jj++) {
      insK(sk[vv][jj][0], k0, k1, k2);
      insK(sk[vv][jj][1], k0, k1, k2);
      insK(sk[vv][jj][2], k0, k1, k2);
    }
    const int base = m * TV + vv;
    if (cnt > 0) {
      unsigned long long ks[3] = {k0, k1, k2};
      #pragma unroll
      for (int r = 0; r < 3; r++) {
        unsigned db = (unsigned)(ks[r] >> 32);
        bool ok = (db != 0xFFFFFFFFu);
        nnD[base*3+r]  = ok ? __uint_as_float(db) : 1e10f;
        nnGI[base*3+r] = ok ? (int)(unsigned)(ks[r] & 0xFFFFFFFFull) : 0;
      }
    } else {
      #pragma unroll
      for (int r = 0; r < 3; r++) { nnD[base*3+r] = -1.0f; nnGI[base*3+r] = 0; }
    }
  }
}

// ---------------- Kernel A3: weights + local_xyz + interp + conv1 (8 queries/block) + BN1 stats ----------------
__global__ __launch_bounds__(256) void kA3(const float* __restrict__ sup_feat,
                                           const float* __restrict__ sup_xyz,
                                           const float* __restrict__ new_xyz,
                                           const float* __restrict__ nnD,
                                           const int*   __restrict__ nnGI,
                                           const float* __restrict__ w1T,
                                           float* __restrict__ y1,
                                           float* __restrict__ stats1)   // [8][2*CH1]
{
  __shared__ float s_feats[8][TV][CIN];   // 35,424 B
  __shared__ float s_w[8][TV][3];
  __shared__ int   s_gi[8][TV][3];

  const int m0  = blockIdx.x * 8;
  const int tid = threadIdx.x;

  // per-(q,v) thread: weights + local_xyz (216 threads)
  if (tid < 8*TV) {
    const int q = tid / TV, vv = tid % TV;
    const int m = m0 + q;
    const int base = m * TV + vv;
    float d[3]; int gi[3];
    #pragma unroll
    for (int r = 0; r < 3; r++) { d[r] = nnD[base*3+r]; gi[r] = nnGI[base*3+r]; }
    #pragma unroll
    for (int r = 0; r < 3; r++) s_gi[q][vv][r] = gi[r];
    if (d[0] < 0.0f) {                           // empty query: zero weights + zero local
      #pragma unroll
      for (int r = 0; r < 3; r++) s_w[q][vv][r] = 0.0f;
      #pragma unroll
      for (int jj = 0; jj < 9; jj++) s_feats[q][vv][32 + jj] = 0.0f;
    } else {
      float r0 = 1.0f / (d[0] + 1e-8f);
      float r1 = 1.0f / (d[1] + 1e-8f);
      float r2 = 1.0f / (d[2] + 1e-8f);
      float den = fmaxf(r0 + r1 + r2, 1e-8f);
      s_w[q][vv][0] = r0 / den; s_w[q][vv][1] = r1 / den; s_w[q][vv][2] = r2 / den;
      const float gx = new_xyz[m*3+0] + gsel(vv / 9);
      const float gy = new_xyz[m*3+1] + gsel((vv / 3) % 3);
      const float gz = new_xyz[m*3+2] + gsel(vv % 3);
      #pragma unroll
      for (int r = 0; r < 3; r++) {
        bool ok = (d[r] != 1e10f);
        s_feats[q][vv][32 + r*3 + 0] = ok ? (gx - sup_xyz[gi[r]*3 + 0]) : 0.0f;
        s_feats[q][vv][32 + r*3 + 1] = ok ? (gy - sup_xyz[gi[r]*3 + 1]) : 0.0f;
        s_feats[q][vv][32 + r*3 + 2] = ok ? (gz - sup_xyz[gi[r]*3 + 2]) : 0.0f;
      }
    }
  }
  __syncthreads();

  // interp: 8*27*32 = 6912 elements
  for (int t = tid; t < 8*TV*32; t += 256) {
    const int q = t / (TV*32), rem = t % (TV*32);
    const int v = rem >> 5, ch = rem & 31;
    s_feats[q][v][ch] = s_w[q][v][0] * sup_feat[s_gi[q][v][0]*32 + ch]
                      + s_w[q][v][1] * sup_feat[s_gi[q][v][1]*32 + ch]
                      + s_w[q][v][2] * sup_feat[s_gi[q][v][2]*32 + ch];
  }
  __syncthreads();

  const int copy = (blockIdx.x & 7) * 2 * CH1;   // spread stat atomics over 8 copies
  for (int t = tid; t < CH1; t += 256) {
    const int v = t >> 5;
    float acc[8];
    #pragma unroll
    for (int q = 0; q < 8; q++) acc[q] = 0.0f;
    for (int k = 0; k < CIN; k++) {
      float w = w1T[k * CH1 + t];
      #pragma unroll
      for (int q = 0; q < 8; q++) acc[q] += s_feats[q][v][k] * w;
    }
    float s = 0.0f, ss = 0.0f;
    #pragma unroll
    for (int q = 0; q < 8; q++) {
      y1[(size_t)(m0 + q) * CH1 + t] = acc[q];
      s += acc[q]; ss += acc[q] * acc[q];
    }
    atomicAdd(&stats1[copy + t],       s);
    atomicAdd(&stats1[copy + CH1 + t], ss);
  }
}

// ---------------- Kernel C: BN1-fused split-K GEMM (kS fused), 32x128 tile, 4x4/thread, grid 512 ----------------
__global__ __launch_bounds__(256) void kC(const float* __restrict__ y1,
                                          const float* __restrict__ stats1,   // [8][2*CH1]
                                          const float* __restrict__ g1,
                                          const float* __restrict__ b1,
                                          const float* __restrict__ w2T,
                                          float* __restrict__ zpart)   // [4][M_Q][CH2]
{
  __shared__ float As[KC_BK][36];      // [k][row], stride 36 (144 B, 16B-aligned rows)
  __shared__ float Bs[KC_BK][CH2];     // 12 KB
  __shared__ float lsc[KC_KS], lsh[KC_KS];

  const int tid = threadIdx.x;
  const int mb  = blockIdx.x & 127;
  const int ch  = blockIdx.x >> 7;
  const int m0  = mb * 32;
  const int kb  = ch * KC_KS;

  // fused kS: BN1 scale/shift for this chunk's 216 channels (sums 8 stat copies)
  for (int t = tid; t < KC_KS; t += 256) {
    const int c = kb + t;
    float s = 0.0f, ssq = 0.0f;
    #pragma unroll
    for (int k = 0; k < 8; k++) {
      s   += stats1[k * 2 * CH1 + c];
      ssq += stats1[k * 2 * CH1 + CH1 + c];
    }
    float mu  = s  * (1.0f / M_Q);
    float var = ssq * (1.0f / M_Q) - mu * mu;
    float r   = 1.0f / sqrtf(var + 1e-5f);
    float gg = g1[c];
    lsc[t] = r * gg;
    lsh[t] = b1[c] - mu * r * gg;
  }

  const int ar = tid >> 3;          // 0..31 A-tile row
  const int ac = (tid & 7) * 3;     // 0..21 A-tile k-offset (3 consecutive)
  const int ty = tid >> 5;          // 0..7  -> rows ty*4..+3
  const int tx = tid & 31;          // 0..31 -> cols tx*4..+3

  // prefetch tile 0
  float pa0, pa1, pa2; float4 pb[3];
  {
    const float* yr = &y1[(size_t)(m0 + ar) * CH1 + kb + ac];
    pa0 = yr[0]; pa1 = yr[1]; pa2 = yr[2];
    #pragma unroll
    for (int jj = 0; jj < 3; jj++) {
      int fid = tid + jj * 256; int kk = fid >> 5, c4 = (fid & 31) * 4;
      pb[jj] = *(const float4*)&w2T[(size_t)(kb + kk) * CH2 + c4];
    }
  }

  float acc[4][4];
  #pragma unroll
  for (int i = 0; i < 4; i++)
    #pragma unroll
    for (int jj = 0; jj < 4; jj++) acc[i][jj] = 0.0f;

  for (int kt = 0; kt < KC_KS / KC_BK; kt++) {
    __syncthreads();                       // previous tile consumed; covers lsc/lsh at kt=0
    const int kl = kt * KC_BK + ac;
    As[ac  ][ar] = fmaxf(pa0 * lsc[kl  ] + lsh[kl  ], 0.0f);
    As[ac+1][ar] = fmaxf(pa1 * lsc[kl+1] + lsh[kl+1], 0.0f);
    As[ac+2][ar] = fmaxf(pa2 * lsc[kl+2] + lsh[kl+2], 0.0f);
    #pragma unroll
    for (int jj = 0; jj < 3; jj++) {
      int fid = tid + jj * 256; int kk = fid >> 5, c4 = (fid & 31) * 4;
      *(float4*)&Bs[kk][c4] = pb[jj];
    }
    __syncthreads();
    if (kt + 1 < KC_KS / KC_BK) {          // prefetch next tile (overlaps compute)
      const float* yr = &y1[(size_t)(m0 + ar) * CH1 + kb + (kt+1) * KC_BK + ac];
      pa0 = yr[0]; pa1 = yr[1]; pa2 = yr[2];
      #pragma unroll
      for (int jj = 0; jj < 3; jj++) {
        int fid = tid + jj * 256; int kk = fid >> 5, c4 = (fid & 31) * 4;
        pb[jj] = *(const float4*)&w2T[(size_t)(kb + (kt+1) * KC_BK + kk) * CH2 + c4];
      }
    }
    #pragma unroll
    for (int kk = 0; kk < KC_BK; kk++) {
      float4 av = *(const float4*)&As[kk][ty*4];
      float4 bv = *(const float4*)&Bs[kk][tx*4];
      acc[0][0] += av.x*bv.x; acc[0][1] += av.x*bv.y; acc[0][2] += av.x*bv.z; acc[0][3] += av.x*bv.w;
      acc[1][0] += av.y*bv.x; acc[1][1] += av.y*bv.y; acc[1][2] += av.y*bv.z; acc[1][3] += av.y*bv.w;
      acc[2][0] += av.z*bv.x; acc[2][1] += av.z*bv.y; acc[2][2] += av.z*bv.z; acc[2][3] += av.z*bv.w;
      acc[3][0] += av.w*bv.x; acc[3][1] += av.w*bv.y; acc[3][2] += av.w*bv.z; acc[3][3] += av.w*bv.w;
    }
  }

  float* zp = zpart + (size_t)ch * M_Q * CH2;
  #pragma unroll
  for (int i = 0; i < 4; i++) {
    *(float4*)&zp[(size_t)(m0 + ty*4 + i) * CH2 + tx*4] =
        make_float4(acc[i][0], acc[i][1], acc[i][2], acc[i][3]);
  }
}

// ---------------- Kernel Z: sum split-K partials -> z, BN2 stats (grid 512) ----------------
__global__ void kZ(const float* __restrict__ zpart,
                   float* __restrict__ z,
                   float* __restrict__ stats2)   // [8][256]
{
  const int tid = threadIdx.x;
  const int c = tid & 127, h = tid >> 7;
  const int m0 = blockIdx.x * 8 + h * 4;
  float s = 0.0f, ss = 0.0f;
  for (int r = 0; r < 4; r++) {
    size_t off = (size_t)(m0 + r) * CH2 + c;
    float v = zpart[off]
            + zpart[off + (size_t)M_Q*CH2]
            + zpart[off + (size_t)2*M_Q*CH2]
            + zpart[off + (size_t)3*M_Q*CH2];
    z[off] = v;
    s += v; ss += v * v;
  }
  const int copy = (blockIdx.x & 7) * 256;
  atomicAdd(&stats2[copy + c],       s);
  atomicAdd(&stats2[copy + 128 + c], ss);
}

// ---------------- Kernel D: BN2 apply + ReLU -> f32 out (float4) ----------------
__global__ void kD(const float* __restrict__ z,
                   const float* __restrict__ stats2,   // [8][256]
                   const float* __restrict__ g2,
                   const float* __restrict__ b2,
                   float* __restrict__ out)
{
  int t4 = blockIdx.x * 256 + threadIdx.x;
  if (t4 >= M_Q * CH2 / 4) return;
  int c = (t4 & 31) * 4;
  float4 zv = *(const float4*)&z[(size_t)t4 * 4];
  float4 sv = make_float4(0,0,0,0), qv = make_float4(0,0,0,0);
  #pragma unroll
  for (int k = 0; k < 8; k++) {
    float4 a = *(const float4*)&stats2[k * 256 + c];
    float4 b = *(const float4*)&stats2[k * 256 + 128 + c];
    sv.x += a.x; sv.y += a.y; sv.z += a.z; sv.w += a.w;
    qv.x += b.x; qv.y += b.y; qv.z += b.z; qv.w += b.w;
  }
  float4 gv = *(const float4*)&g2[c];
  float4 bv = *(const float4*)&b2[c];
  float4 o;
  {
    float mu = sv.x * (1.0f/M_Q), var = qv.x * (1.0f/M_Q) - mu*mu;
    o.x = fmaxf((zv.x - mu) * (1.0f/sqrtf(var + 1e-5f)) * gv.x + bv.x, 0.0f);
  }
  {
    float mu = sv.y * (1.0f/M_Q), var = qv.y * (1.0f/M_Q) - mu*mu;
    o.y = fmaxf((zv.y - mu) * (1.0f/sqrtf(var + 1e-5f)) * gv.y + bv.y, 0.0f);
  }
  {
    float mu = sv.z * (1.0f/M_Q), var = qv.z * (1.0f/M_Q) - mu*mu;
    o.z = fmaxf((zv.z - mu) * (1.0f/sqrtf(var + 1e-5f)) * gv.z + bv.z, 0.0f);
  }
  {
    float mu = sv.w * (1.0f/M_Q), var = qv.w * (1.0f/M_Q) - mu*mu;
    o.w = fmaxf((zv.w - mu) * (1.0f/sqrtf(var + 1e-5f)) * gv.w + bv.w, 0.0f);
  }
  *(float4*)&out[(size_t)t4 * 4] = o;
}

extern "C" void kernel_launch(void* const* d_in, const int* in_sizes, int n_in,
                              void* d_out, int out_size, void* d_ws, size_t ws_size,
                              hipStream_t stream)
{
  const float* sup_xyz  = (const float*)d_in[0];
  const float* sup_feat = (const float*)d_in[1];
  const float* new_xyz  = (const float*)d_in[2];
  const float* w1       = (const float*)d_in[3];
  const float* g1       = (const float*)d_in[4];
  const float* b1       = (const float*)d_in[5];
  const float* w2       = (const float*)d_in[6];
  const float* g2       = (const float*)d_in[7];
  const float* b2       = (const float*)d_in[8];
  float* out = (float*)d_out;

  char* ws = (char*)d_ws;
  float*  y1     = (float*)(ws);                      // 14,155,776 B
  float*  z      = (float*)(ws + 14155776);           //  2,097,152 B (aliased by w1T early)
  float*  w2T    = (float*)(ws + 16252928);           //    442,368 B
  float*  stats1 = (float*)(ws + 16695296);           // 8 x 1728 f32 = 55,296 B
  float*  stats2 = (float*)(ws + 16750592);           // 8 x  256 f32 =  8,192 B
  int*    counts = (int*)  (ws + 16758784);           //        576 B
  int*    cursor = (int*)  (ws + 16759360);           //        576 B
  int*    starts = (int*)  (ws + 16759936);           //        580 B (pad to 16B)
  float4* pxyzs  = (float4*)(ws + 16760528);          //    262,144 B (16B-aligned)
  float*  nnD    = (float*)(ws + 17022672);           //  1,327,104 B
  int*    nnGI   = (int*)  (ws + 18349776);           //  1,327,104 B
  // zpart (4 x 2,097,152 B = 8,388,608 B) aliases nnD/nnGI (dead after kA3) and
  // extends past them; total ws footprint = 17,022,672 + 8,388,608 = 25,411,280 B.
  float*  zpart  = (float*)(ws + 17022672);
  // w1T (141,696 B) aliases z: kA3 (last reader) runs before kC/kZ touch z.
  float*  w1T    = z;

  // zero stats1 + stats2 + counts + cursor in one contiguous memset
  hipMemsetAsync(stats1, 0, 55296 + 8192 + 576 + 576, stream);

  const int PRE_TOT = CIN*CH1 + CH1*CH2;              // covers N_SUP too
  hipLaunchKernelGGL(kPre,    dim3((PRE_TOT + 255) / 256), dim3(256), 0, stream, w1, w1T, w2, w2T, sup_xyz, counts);
  hipLaunchKernelGGL(kScan,   dim3(1),                    dim3(256), 0, stream, counts, starts, cursor);
  hipLaunchKernelGGL(kScatter,dim3((N_SUP + 255) / 256),  dim3(256), 0, stream, sup_xyz, cursor, pxyzs);
  hipLaunchKernelGGL(kA12,    dim3(M_Q),                  dim3(256), 0, stream, pxyzs, starts, new_xyz, nnD, nnGI);
  hipLaunchKernelGGL(kA3,     dim3(M_Q / 8),              dim3(256), 0, stream, sup_feat, sup_xyz, new_xyz, nnD, nnGI, w1T, y1, stats1);
  hipLaunchKernelGGL(kC,      dim3(128 * KC_NCH),         dim3(256), 0, stream, y1, stats1, g1, b1, w2T, zpart);
  hipLaunchKernelGGL(kZ,      dim3(M_Q / 8),              dim3(256), 0, stream, zpart, z, stats2);
  hipLaunchKernelGGL(kD,      dim3(M_Q * CH2 / 4 / 256),  dim3(256), 0, stream, z, stats2, g2, b2, out);
}

// Round 19
// 132.355 us; speedup vs baseline: 1.3557x; 1.0586x over previous
//
#include <hip/hip_runtime.h>
#include <hip/hip_bf16.h>

#define N_SUP 16384
#define M_Q   4096
#define TV    27
#define CIN   41
#define CINP  44          // padded LDS stride (176 B, 16B-aligned rows)
#define CH1   864
#define CH2   128
#define CAP   1024
#define NB    12          // bins per xy axis (width 50/12 = 4.17 >= 4)
#define NSL   9           // candidate-scan slices per voxel (27*9 = 243 threads)

// kC split-K tiling: 32x128 tile, 4x4/thread, BK=24, 4 K-chunks of 216 -> grid 512
#define KC_BK  24
#define KC_KS  216
#define KC_NCH 4

// grid offset value for axis-index 0/1/2 : linspace(-R+R/NV, R-R/NV, 3) = {-1.3333334, 0, +1.3333334}
__device__ __forceinline__ float gsel(int i){
  const float GOFF = (float)(-2.0 + 2.0 / 3.0);   // -1.3333334f (matches f32 linspace endpoint)
  return (i == 0) ? GOFF : ((i == 2) ? -GOFF : 0.0f);
}

__device__ __forceinline__ int binOf(float x){
  int b = (int)(x * (float)(NB / 50.0));
  return (b < 0) ? 0 : ((b > NB - 1) ? NB - 1 : b);
}

// branchless 3-deep insert of u64 key (keeps k0 <= k1 <= k2)
__device__ __forceinline__ void insK(unsigned long long key,
                                     unsigned long long& k0,
                                     unsigned long long& k1,
                                     unsigned long long& k2){
  bool b0 = key < k0, b1 = key < k1, b2 = key < k2;
  k2 = b1 ? k1 : (b2 ? key : k2);
  k1 = b0 ? k0 : (b1 ? key : k1);
  k0 = b0 ? key : k0;
}

// ---------------- Kernel Pre: w1/w2 transpose + support-point bin count (fused) ----------------
__global__ void kPre(const float* __restrict__ w1, float* __restrict__ w1T,
                     const float* __restrict__ w2, float* __restrict__ w2T,
                     const float* __restrict__ sup_xyz, int* __restrict__ counts)
{
  int idx = blockIdx.x * 256 + threadIdx.x;
  if (idx < N_SUP) {
    float x = sup_xyz[3*idx], y = sup_xyz[3*idx+1];
    atomicAdd(&counts[binOf(x) * NB + binOf(y)], 1);
  }
  if (idx < CIN * CH1) {
    int k = idx / CH1, t = idx % CH1;
    w1T[idx] = w1[(size_t)t * CIN + k];
  }
  int j = idx - CIN * CH1;
  if (j >= 0 && j < CH1 * CH2) {
    int k = j / CH2, c = j % CH2;
    w2T[j] = w2[(size_t)c * CH1 + k];
  }
}

__global__ void kScan(const int* __restrict__ counts, int* __restrict__ starts, int* __restrict__ cursor)
{
  __shared__ int sc[NB*NB];
  int t = threadIdx.x;
  if (t < NB*NB) sc[t] = counts[t];
  __syncthreads();
  if (t == 0) {
    int acc = 0;
    for (int b = 0; b < NB*NB; b++) { int c = sc[b]; sc[b] = acc; acc += c; }
  }
  __syncthreads();
  if (t < NB*NB) { starts[t] = sc[t]; cursor[t] = sc[t]; }
  if (t == NB*NB) starts[NB*NB] = N_SUP;
}

__global__ void kScatter(const float* __restrict__ sup_xyz, int* __restrict__ cursor,
                         float4* __restrict__ pxyzs)
{
  int i = blockIdx.x * 256 + threadIdx.x;
  if (i < N_SUP) {
    float x = sup_xyz[3*i], y = sup_xyz[3*i+1], z = sup_xyz[3*i+2];
    int b = binOf(x) * NB + binOf(y);
    int p = atomicAdd(&cursor[b], 1);
    pxyzs[p] = make_float4(x, y, z, __uint_as_float((unsigned)i));
  }
}

// ---------------- Kernel A12: bin-pruned cube filter + per-voxel 3NN (guarded insert) ----------------
// (round-17 proven version: flat scan, bit-exact _rn distance, 9 slices/voxel, packed loads)
__global__ __launch_bounds__(256) void kA12(const float4* __restrict__ pxyzs,
                                            const int*   __restrict__ starts,
                                            const float* __restrict__ new_xyz,
                                            float* __restrict__ nnD,
                                            int*   __restrict__ nnGI)
{
  __shared__ float4 cxyz[CAP];                 // filtered candidates (.w = sid bits)
  __shared__ unsigned long long sk[TV][NSL][3];
  __shared__ int s_cnt;

  const int m   = blockIdx.x;
  const int tid = threadIdx.x;
  if (tid == 0) s_cnt = 0;
  __syncthreads();

  const float qx = new_xyz[m*3+0];
  const float qy = new_xyz[m*3+1];
  const float qz = new_xyz[m*3+2];

  // ---- phase 1: cube filter over <=3x3 bins (z-test vacuous: |dz|<4 always) ----
  const int bx0 = binOf(qx - 4.0f), bx1 = binOf(qx + 4.0f);
  const int by0 = binOf(qy - 4.0f), by1 = binOf(qy + 4.0f);
  for (int bx = bx0; bx <= bx1; bx++) {
    const int beg = starts[bx * NB + by0];
    const int end = starts[bx * NB + by1 + 1];
    for (int i = beg + tid; i < end; i += 256) {
      float4 pt = pxyzs[i];
      if (fabsf(__fsub_rn(pt.x, qx)) <= 4.0f && fabsf(__fsub_rn(pt.y, qy)) <= 4.0f) {
        int p = atomicAdd(&s_cnt, 1);
        if (p < CAP) cxyz[p] = pt;
      }
    }
  }
  __syncthreads();
  const int cnt = (s_cnt < CAP) ? s_cnt : CAP;

  // ---- phase 2a: strided scan, 9 threads per voxel, guarded insert ----
  const int v = tid / NSL, j = tid % NSL;      // 243 active threads
  if (v < TV) {
    const float gx = qx + gsel(v / 9);
    const float gy = qy + gsel((v / 3) % 3);
    const float gz = qz + gsel(v % 3);
    unsigned long long k0 = ~0ull, k1 = ~0ull, k2 = ~0ull;
    float k2df = __uint_as_float(0xFFFFFFFFu);   // NaN sentinel -> insert path until 3 found
    for (int c = j; c < cnt; c += NSL) {
      float4 f4 = cxyz[c];
      float dx = __fsub_rn(gx, f4.x);
      float dy = __fsub_rn(gy, f4.y);
      float dz = __fsub_rn(gz, f4.z);
      // forbid FMA contraction: must match numpy f32 (mul, mul, add, mul, add)
      float dd = __fadd_rn(__fadd_rn(__fmul_rn(dx,dx), __fmul_rn(dy,dy)), __fmul_rn(dz,dz));
      if (!(dd > k2df)) {                        // fast reject; == still takes insert (tie by sid)
        unsigned long long key = ((unsigned long long)__float_as_uint(dd) << 32)
                               | (unsigned long long)__float_as_uint(f4.w); // low = sid
        insK(key, k0, k1, k2);
        k2df = __uint_as_float((unsigned)(k2 >> 32));
      }
    }
    sk[v][j][0] = k0; sk[v][j][1] = k1; sk[v][j][2] = k2;
  }
  __syncthreads();

  // ---- phase 2b: merge 9x3 keys per voxel + dump (d,gi) (threads 0..26) ----
  if (tid < TV) {
    const int vv = tid;
    unsigned long long k0 = ~0ull, k1 = ~0ull, k2 = ~0ull;
    #pragma unroll
    for (int jj = 0; jj < NSL; jj++) {
      insK(sk[vv][jj][0], k0, k1, k2);
      insK(sk[vv][jj][1], k0, k1, k2);
      insK(sk[vv][jj][2], k0, k1, k2);
    }
    const int base = m * TV + vv;
    if (cnt > 0) {
      unsigned long long ks[3] = {k0, k1, k2};
      #pragma unroll
      for (int r = 0; r < 3; r++) {
        unsigned db = (unsigned)(ks[r] >> 32);
        bool ok = (db != 0xFFFFFFFFu);
        nnD[base*3+r]  = ok ? __uint_as_float(db) : 1e10f;
        nnGI[base*3+r] = ok ? (int)(unsigned)(ks[r] & 0xFFFFFFFFull) : 0;
      }
    } else {
      #pragma unroll
      for (int r = 0; r < 3; r++) { nnD[base*3+r] = -1.0f; nnGI[base*3+r] = 0; }
    }
  }
}

// ---------------- Kernel A3: weights + local_xyz + interp + conv1 (8 queries/block) + BN1 stats ----------------
__global__ __launch_bounds__(256) void kA3(const float* __restrict__ sup_feat,
                                           const float* __restrict__ sup_xyz,
                                           const float* __restrict__ new_xyz,
                                           const float* __restrict__ nnD,
                                           const int*   __restrict__ nnGI,
                                           const float* __restrict__ w1T,
                                           float* __restrict__ y1,
                                           float* __restrict__ stats1)   // [8][2*CH1]
{
  __shared__ float s_feats[8][TV][CINP];  // 38,016 B (rows 16B-aligned)
  __shared__ float s_w[8][TV][3];
  __shared__ int   s_gi[8][TV][3];

  const int m0  = blockIdx.x * 8;
  const int tid = threadIdx.x;

  // per-(q,v) thread: weights + local_xyz (216 threads)
  if (tid < 8*TV) {
    const int q = tid / TV, vv = tid % TV;
    const int m = m0 + q;
    const int base = m * TV + vv;
    float d[3]; int gi[3];
    #pragma unroll
    for (int r = 0; r < 3; r++) { d[r] = nnD[base*3+r]; gi[r] = nnGI[base*3+r]; }
    #pragma unroll
    for (int r = 0; r < 3; r++) s_gi[q][vv][r] = gi[r];
    if (d[0] < 0.0f) {                           // empty query: zero weights + zero local
      #pragma unroll
      for (int r = 0; r < 3; r++) s_w[q][vv][r] = 0.0f;
      #pragma unroll
      for (int jj = 0; jj < 9; jj++) s_feats[q][vv][32 + jj] = 0.0f;
    } else {
      float r0 = 1.0f / (d[0] + 1e-8f);
      float r1 = 1.0f / (d[1] + 1e-8f);
      float r2 = 1.0f / (d[2] + 1e-8f);
      float den = fmaxf(r0 + r1 + r2, 1e-8f);
      s_w[q][vv][0] = r0 / den; s_w[q][vv][1] = r1 / den; s_w[q][vv][2] = r2 / den;
      const float gx = new_xyz[m*3+0] + gsel(vv / 9);
      const float gy = new_xyz[m*3+1] + gsel((vv / 3) % 3);
      const float gz = new_xyz[m*3+2] + gsel(vv % 3);
      #pragma unroll
      for (int r = 0; r < 3; r++) {
        bool ok = (d[r] != 1e10f);
        s_feats[q][vv][32 + r*3 + 0] = ok ? (gx - sup_xyz[gi[r]*3 + 0]) : 0.0f;
        s_feats[q][vv][32 + r*3 + 1] = ok ? (gy - sup_xyz[gi[r]*3 + 1]) : 0.0f;
        s_feats[q][vv][32 + r*3 + 2] = ok ? (gz - sup_xyz[gi[r]*3 + 2]) : 0.0f;
      }
    }
  }
  __syncthreads();

  // interp, float4: 8*27*8 = 1728 float4 elements
  const float4* sf4 = (const float4*)sup_feat;
  for (int t = tid; t < 8*TV*8; t += 256) {
    const int q = t / (TV*8), rem = t % (TV*8);
    const int v = rem >> 3, g = rem & 7;        // 8 float4 groups = 32 channels
    float4 a = sf4[s_gi[q][v][0]*8 + g];
    float4 b = sf4[s_gi[q][v][1]*8 + g];
    float4 c = sf4[s_gi[q][v][2]*8 + g];
    float w0 = s_w[q][v][0], w1_ = s_w[q][v][1], w2_ = s_w[q][v][2];
    float4 o;
    o.x = w0*a.x + w1_*b.x + w2_*c.x;
    o.y = w0*a.y + w1_*b.y + w2_*c.y;
    o.z = w0*a.z + w1_*b.z + w2_*c.z;
    o.w = w0*a.w + w1_*b.w + w2_*c.w;
    *(float4*)&s_feats[q][v][g*4] = o;
  }
  __syncthreads();

  const int copy = (blockIdx.x & 7) * 2 * CH1;   // spread stat atomics over 8 copies
  for (int t = tid; t < CH1; t += 256) {
    const int v = t >> 5;
    float acc[8];
    #pragma unroll
    for (int q = 0; q < 8; q++) acc[q] = 0.0f;
    for (int k = 0; k < CIN; k++) {
      float w = w1T[k * CH1 + t];
      #pragma unroll
      for (int q = 0; q < 8; q++) acc[q] += s_feats[q][v][k] * w;
    }
    float s = 0.0f, ss = 0.0f;
    #pragma unroll
    for (int q = 0; q < 8; q++) {
      y1[(size_t)(m0 + q) * CH1 + t] = acc[q];
      s += acc[q]; ss += acc[q] * acc[q];
    }
    atomicAdd(&stats1[copy + t],       s);
    atomicAdd(&stats1[copy + CH1 + t], ss);
  }
}

// ---------------- Kernel C: BN1-fused split-K GEMM (kS fused), 32x128 tile, 4x4/thread, grid 512 ----------------
__global__ __launch_bounds__(256) void kC(const float* __restrict__ y1,
                                          const float* __restrict__ stats1,   // [8][2*CH1]
                                          const float* __restrict__ g1,
                                          const float* __restrict__ b1,
                                          const float* __restrict__ w2T,
                                          float* __restrict__ zpart)   // [4][M_Q][CH2]
{
  __shared__ float As[KC_BK][36];      // [k][row], stride 36 (144 B, 16B-aligned rows)
  __shared__ float Bs[KC_BK][CH2];     // 12 KB
  __shared__ float lsc[KC_KS], lsh[KC_KS];

  const int tid = threadIdx.x;
  const int mb  = blockIdx.x & 127;
  const int ch  = blockIdx.x >> 7;
  const int m0  = mb * 32;
  const int kb  = ch * KC_KS;

  // fused kS: BN1 scale/shift for this chunk's 216 channels (sums 8 stat copies)
  for (int t = tid; t < KC_KS; t += 256) {
    const int c = kb + t;
    float s = 0.0f, ssq = 0.0f;
    #pragma unroll
    for (int k = 0; k < 8; k++) {
      s   += stats1[k * 2 * CH1 + c];
      ssq += stats1[k * 2 * CH1 + CH1 + c];
    }
    float mu  = s  * (1.0f / M_Q);
    float var = ssq * (1.0f / M_Q) - mu * mu;
    float r   = 1.0f / sqrtf(var + 1e-5f);
    float gg = g1[c];
    lsc[t] = r * gg;
    lsh[t] = b1[c] - mu * r * gg;
  }

  const int ar = tid >> 3;          // 0..31 A-tile row
  const int ac = (tid & 7) * 3;     // 0..21 A-tile k-offset (3 consecutive)
  const int ty = tid >> 5;          // 0..7  -> rows ty*4..+3
  const int tx = tid & 31;          // 0..31 -> cols tx*4..+3

  // prefetch tile 0
  float pa0, pa1, pa2; float4 pb[3];
  {
    const float* yr = &y1[(size_t)(m0 + ar) * CH1 + kb + ac];
    pa0 = yr[0]; pa1 = yr[1]; pa2 = yr[2];
    #pragma unroll
    for (int jj = 0; jj < 3; jj++) {
      int fid = tid + jj * 256; int kk = fid >> 5, c4 = (fid & 31) * 4;
      pb[jj] = *(const float4*)&w2T[(size_t)(kb + kk) * CH2 + c4];
    }
  }

  float acc[4][4];
  #pragma unroll
  for (int i = 0; i < 4; i++)
    #pragma unroll
    for (int jj = 0; jj < 4; jj++) acc[i][jj] = 0.0f;

  for (int kt = 0; kt < KC_KS / KC_BK; kt++) {
    __syncthreads();                       // previous tile consumed; covers lsc/lsh at kt=0
    const int kl = kt * KC_BK + ac;
    As[ac  ][ar] = fmaxf(pa0 * lsc[kl  ] + lsh[kl  ], 0.0f);
    As[ac+1][ar] = fmaxf(pa1 * lsc[kl+1] + lsh[kl+1], 0.0f);
    As[ac+2][ar] = fmaxf(pa2 * lsc[kl+2] + lsh[kl+2], 0.0f);
    #pragma unroll
    for (int jj = 0; jj < 3; jj++) {
      int fid = tid + jj * 256; int kk = fid >> 5, c4 = (fid & 31) * 4;
      *(float4*)&Bs[kk][c4] = pb[jj];
    }
    __syncthreads();
    if (kt + 1 < KC_KS / KC_BK) {          // prefetch next tile (overlaps compute)
      const float* yr = &y1[(size_t)(m0 + ar) * CH1 + kb + (kt+1) * KC_BK + ac];
      pa0 = yr[0]; pa1 = yr[1]; pa2 = yr[2];
      #pragma unroll
      for (int jj = 0; jj < 3; jj++) {
        int fid = tid + jj * 256; int kk = fid >> 5, c4 = (fid & 31) * 4;
        pb[jj] = *(const float4*)&w2T[(size_t)(kb + (kt+1) * KC_BK + kk) * CH2 + c4];
      }
    }
    #pragma unroll
    for (int kk = 0; kk < KC_BK; kk++) {
      float4 av = *(const float4*)&As[kk][ty*4];
      float4 bv = *(const float4*)&Bs[kk][tx*4];
      acc[0][0] += av.x*bv.x; acc[0][1] += av.x*bv.y; acc[0][2] += av.x*bv.z; acc[0][3] += av.x*bv.w;
      acc[1][0] += av.y*bv.x; acc[1][1] += av.y*bv.y; acc[1][2] += av.y*bv.z; acc[1][3] += av.y*bv.w;
      acc[2][0] += av.z*bv.x; acc[2][1] += av.z*bv.y; acc[2][2] += av.z*bv.z; acc[2][3] += av.z*bv.w;
      acc[3][0] += av.w*bv.x; acc[3][1] += av.w*bv.y; acc[3][2] += av.w*bv.z; acc[3][3] += av.w*bv.w;
    }
  }

  float* zp = zpart + (size_t)ch * M_Q * CH2;
  #pragma unroll
  for (int i = 0; i < 4; i++) {
    *(float4*)&zp[(size_t)(m0 + ty*4 + i) * CH2 + tx*4] =
        make_float4(acc[i][0], acc[i][1], acc[i][2], acc[i][3]);
  }
}

// ---------------- Kernel Z: sum split-K partials -> z, BN2 stats (grid 512) ----------------
__global__ void kZ(const float* __restrict__ zpart,
                   float* __restrict__ z,
                   float* __restrict__ stats2)   // [8][256]
{
  const int tid = threadIdx.x;
  const int c = tid & 127, h = tid >> 7;
  const int m0 = blockIdx.x * 8 + h * 4;
  float s = 0.0f, ss = 0.0f;
  for (int r = 0; r < 4; r++) {
    size_t off = (size_t)(m0 + r) * CH2 + c;
    float v = zpart[off]
            + zpart[off + (size_t)M_Q*CH2]
            + zpart[off + (size_t)2*M_Q*CH2]
            + zpart[off + (size_t)3*M_Q*CH2];
    z[off] = v;
    s += v; ss += v * v;
  }
  const int copy = (blockIdx.x & 7) * 256;
  atomicAdd(&stats2[copy + c],       s);
  atomicAdd(&stats2[copy + 128 + c], ss);
}

// ---------------- Kernel D: BN2 apply + ReLU -> f32 out (float4) ----------------
__global__ void kD(const float* __restrict__ z,
                   const float* __restrict__ stats2,   // [8][256]
                   const float* __restrict__ g2,
                   const float* __restrict__ b2,
                   float* __restrict__ out)
{
  int t4 = blockIdx.x * 256 + threadIdx.x;
  if (t4 >= M_Q * CH2 / 4) return;
  int c = (t4 & 31) * 4;
  float4 zv = *(const float4*)&z[(size_t)t4 * 4];
  float4 sv = make_float4(0,0,0,0), qv = make_float4(0,0,0,0);
  #pragma unroll
  for (int k = 0; k < 8; k++) {
    float4 a = *(const float4*)&stats2[k * 256 + c];
    float4 b = *(const float4*)&stats2[k * 256 + 128 + c];
    sv.x += a.x; sv.y += a.y; sv.z += a.z; sv.w += a.w;
    qv.x += b.x; qv.y += b.y; qv.z += b.z; qv.w += b.w;
  }
  float4 gv = *(const float4*)&g2[c];
  float4 bv = *(const float4*)&b2[c];
  float4 o;
  {
    float mu = sv.x * (1.0f/M_Q), var = qv.x * (1.0f/M_Q) - mu*mu;
    o.x = fmaxf((zv.x - mu) * (1.0f/sqrtf(var + 1e-5f)) * gv.x + bv.x, 0.0f);
  }
  {
    float mu = sv.y * (1.0f/M_Q), var = qv.y * (1.0f/M_Q) - mu*mu;
    o.y = fmaxf((zv.y - mu) * (1.0f/sqrtf(var + 1e-5f)) * gv.y + bv.y, 0.0f);
  }
  {
    float mu = sv.z * (1.0f/M_Q), var = qv.z * (1.0f/M_Q) - mu*mu;
    o.z = fmaxf((zv.z - mu) * (1.0f/sqrtf(var + 1e-5f)) * gv.z + bv.z, 0.0f);
  }
  {
    float mu = sv.w * (1.0f/M_Q), var = qv.w * (1.0f/M_Q) - mu*mu;
    o.w = fmaxf((zv.w - mu) * (1.0f/sqrtf(var + 1e-5f)) * gv.w + bv.w, 0.0f);
  }
  *(float4*)&out[(size_t)t4 * 4] = o;
}

extern "C" void kernel_launch(void* const* d_in, const int* in_sizes, int n_in,
                              void* d_out, int out_size, void* d_ws, size_t ws_size,
                              hipStream_t stream)
{
  const float* sup_xyz  = (const float*)d_in[0];
  const float* sup_feat = (const float*)d_in[1];
  const float* new_xyz  = (const float*)d_in[2];
  const float* w1       = (const float*)d_in[3];
  const float* g1       = (const float*)d_in[4];
  const float* b1       = (const float*)d_in[5];
  const float* w2       = (const float*)d_in[6];
  const float* g2       = (const float*)d_in[7];
  const float* b2       = (const float*)d_in[8];
  float* out = (float*)d_out;

  char* ws = (char*)d_ws;
  float*  y1     = (float*)(ws);                      // 14,155,776 B
  float*  z      = (float*)(ws + 14155776);           //  2,097,152 B (aliased by w1T early)
  float*  w2T    = (float*)(ws + 16252928);           //    442,368 B
  float*  stats1 = (float*)(ws + 16695296);           // 8 x 1728 f32 = 55,296 B
  float*  stats2 = (float*)(ws + 16750592);           // 8 x  256 f32 =  8,192 B
  int*    counts = (int*)  (ws + 16758784);           //        576 B
  int*    cursor = (int*)  (ws + 16759360);           //        576 B
  int*    starts = (int*)  (ws + 16759936);           //        580 B (pad to 16B)
  float4* pxyzs  = (float4*)(ws + 16760528);          //    262,144 B (16B-aligned)
  float*  nnD    = (float*)(ws + 17022672);           //  1,327,104 B
  int*    nnGI   = (int*)  (ws + 18349776);           //  1,327,104 B
  // zpart (4 x 2,097,152 B = 8,388,608 B) aliases nnD/nnGI (dead after kA3) and
  // extends past them; total ws footprint = 17,022,672 + 8,388,608 = 25,411,280 B.
  float*  zpart  = (float*)(ws + 17022672);
  // w1T (141,696 B) aliases z: kA3 (last reader) runs before kC/kZ touch z.
  float*  w1T    = z;

  // zero stats1 + stats2 + counts + cursor in one contiguous memset
  hipMemsetAsync(stats1, 0, 55296 + 8192 + 576 + 576, stream);

  const int PRE_TOT = CIN*CH1 + CH1*CH2;              // covers N_SUP too
  hipLaunchKernelGGL(kPre,    dim3((PRE_TOT + 255) / 256), dim3(256), 0, stream, w1, w1T, w2, w2T, sup_xyz, counts);
  hipLaunchKernelGGL(kScan,   dim3(1),                    dim3(256), 0, stream, counts, starts, cursor);
  hipLaunchKernelGGL(kScatter,dim3((N_SUP + 255) / 256),  dim3(256), 0, stream, sup_xyz, cursor, pxyzs);
  hipLaunchKernelGGL(kA12,    dim3(M_Q),                  dim3(256), 0, stream, pxyzs, starts, new_xyz, nnD, nnGI);
  hipLaunchKernelGGL(kA3,     dim3(M_Q / 8),              dim3(256), 0, stream, sup_feat, sup_xyz, new_xyz, nnD, nnGI, w1T, y1, stats1);
  hipLaunchKernelGGL(kC,      dim3(128 * KC_NCH),         dim3(256), 0, stream, y1, stats1, g1, b1, w2T, zpart);
  hipLaunchKernelGGL(kZ,      dim3(M_Q / 8),              dim3(256), 0, stream, zpart, z, stats2);
  hipLaunchKernelGGL(kD,      dim3(M_Q * CH2 / 4 / 256),  dim3(256), 0, stream, z, stats2, g2, b2, out);
}